// Round 4
// baseline (625.091 us; speedup 1.0000x reference)
//
#include <hip/hip_runtime.h>

#define S_LEN 2048
#define BATCH 2
#define HID 4096
#define NH 32
#define NKV 8
#define DH 128
#define MROWS (BATCH*S_LEN)   // 4096
#define QKV_N 6144

typedef unsigned short u16;
typedef unsigned int u32;
typedef __bf16 bf16x8 __attribute__((ext_vector_type(8)));
typedef float f32x4 __attribute__((ext_vector_type(4)));
typedef u16 u16x8 __attribute__((ext_vector_type(8)));

__device__ __forceinline__ u16 f2bf(float f) {           // round-half-up (2 insts)
  union { float f; u32 u; } v; v.f = f;
  return (u16)((v.u + 0x8000u) >> 16);
}
__device__ __forceinline__ float bf2f(u16 h) {
  union { u32 u; float f; } v; v.u = ((u32)h) << 16;
  return v.f;
}
__device__ __forceinline__ u32 cvtpk(float a, float b) { // packs bf16(a)|bf16(b)<<16
  u32 r;
  asm("v_cvt_pk_bf16_f32 %0, %1, %2" : "=v"(r) : "v"(a), "v"(b));
  return r;
}
__device__ __forceinline__ void async16(const void* g, void* l) {
  __builtin_amdgcn_global_load_lds(
      (const __attribute__((address_space(1))) u32*)g,
      (__attribute__((address_space(3))) u32*)l, 16, 0, 0);
}
__device__ __forceinline__ f32x4 mfma16(bf16x8 a, bf16x8 b, f32x4 c) {
  return __builtin_amdgcn_mfma_f32_16x16x32_bf16(a, b, c, 0, 0, 0);
}

// ---------------- fp32 -> bf16 conversion ----------------
__global__ __launch_bounds__(256) void cvt_f32_bf16(const float* __restrict__ in,
                                                    u16* __restrict__ out, int n) {
  int i0 = (blockIdx.x * 256 + threadIdx.x) * 8;
  if (i0 >= n) return;
  float4 a = *(const float4*)(in + i0);
  float4 b = *(const float4*)(in + i0 + 4);
  u16x8 r;
  r[0]=f2bf(a.x); r[1]=f2bf(a.y); r[2]=f2bf(a.z); r[3]=f2bf(a.w);
  r[4]=f2bf(b.x); r[5]=f2bf(b.y); r[6]=f2bf(b.z); r[7]=f2bf(b.w);
  *(u16x8*)(out + i0) = r;
}

// ---------------- 256x256 8-phase NT bf16 GEMM: C[M,N] = A[M,K] * B[N,K]^T ----
// 512 thr = 8 waves (2M x 4N); BK=64; per-wave C = 128x64 (8x4 frags 16x16).
// LDS 128KB: [dbuf2][half2][128x64] per matrix, st_16x32 XOR swizzle.
// Per phase: {ds_read subtile | stage 1 half-tile -> barrier -> MFMA(16) -> barrier},
// counted vmcnt(4) once per K-tile (stages target regions consumed >=1 barrier ago;
// newest 2 stages = 4 loads may stay in flight).
// Stage schedule for K-tile k (buf c=k&1):  P1: (k+1).A0  P2: (k+1).A1
//                                           P3: (k+2).B0  P4: (k+2).B1 + vmcnt(4)
// (k+1 -> buf c^1, free since k-1 fully consumed; k+2 -> buf c, B regions of k
//  fully read after P2, A after P3 — each stage is >=1 barrier after last read.)
template<int OUT_BF16>
__global__ __launch_bounds__(512, 2) void gemm256(
    const u16* __restrict__ A, const u16* __restrict__ B, void* __restrict__ Cout,
    int M, int N, int K) {
  __shared__ u16 As[2][2][64 * 128];   // [dbuf][half][128 rows x 64 cols]
  __shared__ u16 Bs[2][2][64 * 128];
  const int NKT = K >> 6;              // K-tiles of 64 (requires NKT >= 2)
  int nTN = N >> 8;
  int nwg = gridDim.x;
  int id = ((int)blockIdx.x & 7) * (nwg >> 3) + ((int)blockIdx.x >> 3); // XCD swizzle
  int tm = id / nTN, tn = id % nTN;
  int m0 = tm << 8, n0 = tn << 8;
  int t = threadIdx.x;
  int w = t >> 6, lane = t & 63, lo = lane & 15, hi = lane >> 4;
  int wm = w >> 2, wn = w & 3;
  int rbb = (wn & 1) << 6;

  // staging geometry: thread covers 16B chunk; row = c2*64 + w*8 + lane/8
  int srow = (w << 3) + (lane >> 3);
  int scol = (lane & 7) << 3;          // u16 col base of 8-elem chunk

  auto stageA = [&](int kt, int buf, int h) {
#pragma unroll
    for (int c2 = 0; c2 < 2; ++c2) {
      int row = (c2 << 6) + srow;
      int col = scol ^ ((row & 4) << 2);          // inverse swizzle on source
      async16(A + (size_t)(m0 + (h << 7) + row) * K + (kt << 6) + col,
              (char*)&As[buf][h][0] + (c2 << 13) + (w << 10));
    }
  };
  auto stageB = [&](int kt, int buf, int h) {
#pragma unroll
    for (int c2 = 0; c2 < 2; ++c2) {
      int row = (c2 << 6) + srow;
      int col = scol ^ ((row & 4) << 2);
      async16(B + (size_t)(n0 + (h << 7) + row) * K + (kt << 6) + col,
              (char*)&Bs[buf][h][0] + (c2 << 13) + (w << 10));
    }
  };

  const f32x4 fz = {0.f, 0.f, 0.f, 0.f};
  f32x4 acc[8][4];
#pragma unroll
  for (int i = 0; i < 8; ++i)
#pragma unroll
    for (int j = 0; j < 4; ++j) acc[i][j] = fz;
  bf16x8 af[4][2], bfr[4][2];

  // prologue: k0 complete (8 loads) + k1.B (4 loads); wait first 8, keep 4 in flight
  stageB(0, 0, 0); stageB(0, 0, 1);
  stageA(0, 0, 0); stageA(0, 0, 1);
  stageB(1, 1, 0); stageB(1, 1, 1);
  asm volatile("s_waitcnt vmcnt(4)" ::: "memory");
  __builtin_amdgcn_s_barrier();

  for (int kt = 0; kt < NKT; ++kt) {
    int c = kt & 1;
    const u16* Ab = &As[c][wm][0];
    const u16* Bb = &Bs[c][wn >> 1][0];
    int kn1 = (kt + 1 == NKT) ? 0 : kt + 1;            // wrap: redundant but uniform
    int kn2 = (kt + 2 >= NKT) ? kt + 2 - NKT : kt + 2;

    // ---- P1: read A(Mf0-3) + B(Nf0-1); stage (k+1).A0; MFMA Q(0,0)
#pragma unroll
    for (int mf = 0; mf < 4; ++mf)
#pragma unroll
      for (int ks = 0; ks < 2; ++ks) {
        int ra = (mf << 4) + lo;
        af[mf][ks] = *(const bf16x8*)(Ab + (ra << 6) +
                      (((ks << 5) + (hi << 3)) ^ ((ra & 4) << 2)));
      }
#pragma unroll
    for (int nf = 0; nf < 2; ++nf)
#pragma unroll
      for (int ks = 0; ks < 2; ++ks) {
        int rb = rbb + (nf << 4) + lo;
        bfr[nf][ks] = *(const bf16x8*)(Bb + (rb << 6) +
                      (((ks << 5) + (hi << 3)) ^ ((rb & 4) << 2)));
      }
    stageA(kn1, c ^ 1, 0);
    __builtin_amdgcn_s_barrier();
    __builtin_amdgcn_s_setprio(1);
#pragma unroll
    for (int mf = 0; mf < 4; ++mf)
#pragma unroll
      for (int nf = 0; nf < 2; ++nf)
#pragma unroll
        for (int ks = 0; ks < 2; ++ks)
          acc[mf][nf] = mfma16(af[mf][ks], bfr[nf][ks], acc[mf][nf]);
    __builtin_amdgcn_s_setprio(0);
    __builtin_amdgcn_s_barrier();

    // ---- P2: read B(Nf2-3); stage (k+1).A1; MFMA Q(0,1)
#pragma unroll
    for (int nf = 0; nf < 2; ++nf)
#pragma unroll
      for (int ks = 0; ks < 2; ++ks) {
        int rb = rbb + ((nf + 2) << 4) + lo;
        bfr[nf + 2][ks] = *(const bf16x8*)(Bb + (rb << 6) +
                      (((ks << 5) + (hi << 3)) ^ ((rb & 4) << 2)));
      }
    stageA(kn1, c ^ 1, 1);
    __builtin_amdgcn_s_barrier();
    __builtin_amdgcn_s_setprio(1);
#pragma unroll
    for (int mf = 0; mf < 4; ++mf)
#pragma unroll
      for (int nf = 0; nf < 2; ++nf)
#pragma unroll
        for (int ks = 0; ks < 2; ++ks)
          acc[mf][nf + 2] = mfma16(af[mf][ks], bfr[nf + 2][ks], acc[mf][nf + 2]);
    __builtin_amdgcn_s_setprio(0);
    __builtin_amdgcn_s_barrier();

    // ---- P3: read A(Mf4-7); stage (k+2).B0; MFMA Q(1,1)
#pragma unroll
    for (int mf = 0; mf < 4; ++mf)
#pragma unroll
      for (int ks = 0; ks < 2; ++ks) {
        int ra = 64 + (mf << 4) + lo;
        af[mf][ks] = *(const bf16x8*)(Ab + (ra << 6) +
                      (((ks << 5) + (hi << 3)) ^ ((ra & 4) << 2)));
      }
    stageB(kn2, c, 0);
    __builtin_amdgcn_s_barrier();
    __builtin_amdgcn_s_setprio(1);
#pragma unroll
    for (int mf = 0; mf < 4; ++mf)
#pragma unroll
      for (int nf = 0; nf < 2; ++nf)
#pragma unroll
        for (int ks = 0; ks < 2; ++ks)
          acc[mf + 4][nf + 2] = mfma16(af[mf][ks], bfr[nf + 2][ks], acc[mf + 4][nf + 2]);
    __builtin_amdgcn_s_setprio(0);
    __builtin_amdgcn_s_barrier();

    // ---- P4: stage (k+2).B1; MFMA Q(1,0); vmcnt(4) once per K-tile
    stageB(kn2, c, 1);
    __builtin_amdgcn_s_barrier();
    __builtin_amdgcn_s_setprio(1);
#pragma unroll
    for (int mf = 0; mf < 4; ++mf)
#pragma unroll
      for (int nf = 0; nf < 2; ++nf)
#pragma unroll
        for (int ks = 0; ks < 2; ++ks)
          acc[mf + 4][nf] = mfma16(af[mf][ks], bfr[nf][ks], acc[mf + 4][nf]);
    __builtin_amdgcn_s_setprio(0);
    asm volatile("s_waitcnt vmcnt(4)" ::: "memory");
    __builtin_amdgcn_s_barrier();
  }

  // epilogue
#pragma unroll
  for (int mf = 0; mf < 8; ++mf)
#pragma unroll
    for (int nf = 0; nf < 4; ++nf)
#pragma unroll
      for (int r = 0; r < 4; ++r) {
        int row = m0 + (wm << 7) + (mf << 4) + (hi << 2) + r;
        int col = n0 + (wn << 6) + (nf << 4) + lo;
        if (OUT_BF16) ((u16*)Cout)[(size_t)row * N + col] = f2bf(acc[mf][nf][r]);
        else          ((float*)Cout)[(size_t)row * N + col] = acc[mf][nf][r];
      }
}

// ---------------- RoPE (in-place on bf16, optional output scale) ----------------
__global__ __launch_bounds__(256) void rope_kernel(u16* __restrict__ X,
                                                   const int* __restrict__ pos,
                                                   int ncols, int pitch, float scale) {
  int idx = blockIdx.x * 256 + threadIdx.x;
  int groups = ncols >> 3;
  int m = idx / groups;
  int gi = idx - m * groups;
  if (m >= MROWS) return;
  int head = gi >> 4;
  int d0 = (gi & 15) << 2;
  float p = (float)pos[m];
  u16* base = X + (size_t)m * pitch + head * 128;
  u16 xa[4], xb[4], oa[4], ob[4];
  *(uint2*)xa = *(const uint2*)(base + d0);
  *(uint2*)xb = *(const uint2*)(base + d0 + 64);
#pragma unroll
  for (int i = 0; i < 4; ++i) {
    float j = (float)(d0 + i);
    float inv = __expf(j * -0.14391156516030342f);  // ln(10000)/64
    float fr = p * inv;
    float s, c;
    sincosf(fr, &s, &c);
    float x1 = bf2f(xa[i]), x2 = bf2f(xb[i]);
    oa[i] = f2bf((x1 * c - x2 * s) * scale);
    ob[i] = f2bf((x2 * c + x1 * s) * scale);
  }
  *(uint2*)(base + d0) = *(uint2*)oa;
  *(uint2*)(base + d0 + 64) = *(uint2*)ob;
}

// ---------------- V transpose: QKV[m][5120 + g*128 + d] -> Vt[(b*8+g)*128 + d][s] ----------------
__global__ __launch_bounds__(256) void transpose_v(const u16* __restrict__ V,
                                                   u16* __restrict__ Vt) {
  int bid = blockIdx.x;
  int s0 = (bid & 31) << 6;
  int bg = bid >> 5;
  int b = bg >> 3, g = bg & 7;
  __shared__ u16 tile[64][128];
  int t = threadIdx.x;
#pragma unroll
  for (int r = 0; r < 4; ++r) {
    int c = (r << 8) + t;
    int row = c >> 4, cc = c & 15;
    *(uint4*)&tile[row][cc * 8] =
        *(const uint4*)(V + (size_t)(b * S_LEN + s0 + row) * QKV_N + g * 128 + cc * 8);
  }
  __syncthreads();
#pragma unroll
  for (int r = 0; r < 4; ++r) {
    int c = (r << 8) + t;
    int d = c >> 3, cs = c & 7;
    u16 tmp[8];
#pragma unroll
    for (int i = 0; i < 8; ++i) tmp[i] = tile[cs * 8 + i][d];
    *(uint4*)(Vt + ((size_t)bg * 128 + d) * S_LEN + s0 + cs * 8) = *(uint4*)tmp;
  }
}

// ---------------- Flash attention (causal, GQA 4:1), swapped-operand layout ----------------
__global__ __launch_bounds__(256) void attn_kernel(
    const u16* __restrict__ Q, const u16* __restrict__ K,
    const u16* __restrict__ Vt, u16* __restrict__ O) {
  int bid = blockIdx.x;
  int qt = 31 - (bid >> 6);          // heavy tiles first
  int bh = bid & 63;
  int b = bh >> 5, h = bh & 31;
  int g = h >> 2;
  __shared__ u16 Kl[64 * 128];
  __shared__ u16 Vl[128 * 64];
  __shared__ u16 Pl[4][16 * 72];     // per-wave P^T / O-bounce, pitch 72
  int t = threadIdx.x, w = t >> 6, lane = t & 63, lo = lane & 15, hi = lane >> 4;

  bf16x8 qf[4];   // B-operand: lane -> Q row (q=lo)
  {
    const u16* qb = Q + (size_t)(b * S_LEN + (qt << 6) + (w << 4) + lo) * QKV_N + h * 128;
#pragma unroll
    for (int kk = 0; kk < 4; ++kk) qf[kk] = *(const bf16x8*)(qb + kk * 32 + hi * 8);
  }
  const f32x4 fz = {0.f, 0.f, 0.f, 0.f};
  f32x4 acc[8];
#pragma unroll
  for (int f = 0; f < 8; ++f) acc[f] = fz;
  float mrun = -1e30f, lrun = 0.f;

  const u16* Kbase = K + (size_t)(b * S_LEN) * QKV_N + g * 128;
  const u16* Vbase = Vt + (size_t)((b << 3) + g) * 128 * S_LEN;

  int ntiles = qt + 1;
  for (int tile = 0; tile < ntiles; ++tile) {
    int s0 = tile << 6;
#pragma unroll
    for (int r = 0; r < 4; ++r) {              // stage K tile [64][128], chunk-swizzled
      int c = (r << 8) + (w << 6) + lane;
      int row = c >> 4, cc = c & 15;
      int src = cc ^ (row & 7);
      async16(Kbase + (size_t)(s0 + row) * QKV_N + src * 8,
              (char*)Kl + (r << 12) + (w << 10));
    }
#pragma unroll
    for (int r = 0; r < 4; ++r) {              // stage V^T tile [128][64], chunk-swizzled
      int c = (r << 8) + (w << 6) + lane;
      int row = c >> 3, cc = c & 7;
      int src = cc ^ (row & 7);
      async16(Vbase + (size_t)row * S_LEN + s0 + src * 8,
              (char*)Vl + (r << 12) + (w << 10));
    }
    __syncthreads();

    f32x4 sf[4];
#pragma unroll
    for (int j = 0; j < 4; ++j) {
      f32x4 sv = fz;
#pragma unroll
      for (int kk = 0; kk < 4; ++kk) {
        int row = (j << 4) + lo;
        int ch = ((kk << 2) + hi) ^ (row & 7);
        bf16x8 kf = *(const bf16x8*)(Kl + row * 128 + ch * 8);
        sv = __builtin_amdgcn_mfma_f32_16x16x32_bf16(kf, qf[kk], sv, 0, 0, 0);
      }
      sf[j] = sv;
    }
    if (tile == qt) {                           // causal mask on diagonal tile
      int q_rel = (w << 4) + lo;
#pragma unroll
      for (int j = 0; j < 4; ++j)
#pragma unroll
        for (int r = 0; r < 4; ++r)
          if (((j << 4) + (hi << 2) + r) > q_rel) sf[j][r] = -1e9f;
    }
    float pmax = sf[0][0];
#pragma unroll
    for (int j = 0; j < 4; ++j)
#pragma unroll
      for (int r = 0; r < 4; ++r) pmax = fmaxf(pmax, sf[j][r]);
    pmax = fmaxf(pmax, __shfl_xor(pmax, 16, 64));
    pmax = fmaxf(pmax, __shfl_xor(pmax, 32, 64));
    if (__any(pmax > mrun + 8.f)) {             // defer-max rescale (THR=8)
      float mn = fmaxf(mrun, pmax);
      float fsc = __expf(mrun - mn);
      mrun = mn;
      lrun *= fsc;
#pragma unroll
      for (int f = 0; f < 8; ++f)
#pragma unroll
        for (int r = 0; r < 4; ++r) acc[f][r] *= fsc;
    }
    float psum = 0.f;
#pragma unroll
    for (int j = 0; j < 4; ++j)
#pragma unroll
      for (int r = 0; r < 4; ++r) {
        float p = __expf(sf[j][r] - mrun);
        sf[j][r] = p;
        psum += p;
      }
    psum += __shfl_xor(psum, 16, 64);
    psum += __shfl_xor(psum, 32, 64);
    lrun += psum;

#pragma unroll
    for (int j = 0; j < 4; ++j) {
      uint2 pk;
      pk.x = cvtpk(sf[j][0], sf[j][1]);
      pk.y = cvtpk(sf[j][2], sf[j][3]);
      *(uint2*)&Pl[w][lo * 72 + (j << 4) + (hi << 2)] = pk;
    }
#pragma unroll
    for (int kk = 0; kk < 2; ++kk) {
      bf16x8 pf = *(const bf16x8*)&Pl[w][lo * 72 + (kk << 5) + (hi << 3)];
#pragma unroll
      for (int f = 0; f < 8; ++f) {
        int vrow = (f << 4) + lo;
        int phys = ((kk << 2) + hi) ^ (vrow & 7);
        bf16x8 vf = *(const bf16x8*)(Vl + vrow * 64 + phys * 8);
        acc[f] = __builtin_amdgcn_mfma_f32_16x16x32_bf16(vf, pf, acc[f], 0, 0, 0);
      }
    }
    __syncthreads();
  }

  float rl = 1.0f / lrun;
#pragma unroll
  for (int half = 0; half < 2; ++half) {
#pragma unroll
    for (int f2 = 0; f2 < 4; ++f2) {
      int f = (half << 2) + f2;
      uint2 pk;
      pk.x = cvtpk(acc[f][0] * rl, acc[f][1] * rl);
      pk.y = cvtpk(acc[f][2] * rl, acc[f][3] * rl);
      *(uint2*)&Pl[w][lo * 72 + (f2 << 4) + (hi << 2)] = pk;
    }
#pragma unroll
    for (int it = 0; it < 2; ++it) {
      int rowq = (lane >> 3) + (it << 3);
      int c8 = lane & 7;
      uint4 val = *(const uint4*)&Pl[w][rowq * 72 + c8 * 8];
      *(uint4*)(O + (size_t)(b * S_LEN + (qt << 6) + (w << 4) + rowq) * 4096 +
                h * 128 + (half << 6) + c8 * 8) = val;
    }
  }
}

// ---------------- launch ----------------
extern "C" void kernel_launch(void* const* d_in, const int* in_sizes, int n_in,
                              void* d_out, int out_size, void* d_ws, size_t ws_size,
                              hipStream_t stream) {
  const float* hidden = (const float*)d_in[0];
  const int* pos = (const int*)d_in[1];
  const float* Wq = (const float*)d_in[2];
  const float* Wk = (const float*)d_in[3];
  const float* Wv = (const float*)d_in[4];
  const float* Wo = (const float*)d_in[5];
  float* out = (float*)d_out;

  u16* hb   = (u16*)d_ws;                 // [4096][4096]
  u16* wqb  = hb   + 16777216;            // [4096][4096]  } contiguous -> fused
  u16* wkb  = wqb  + 16777216;            // [1024][4096]  }   B matrix [6144][4096]
  u16* wvb  = wkb  + 4194304;             // [1024][4096]  }
  u16* wob  = wvb  + 4194304;             // [4096][4096]
  u16* QKVb = wob  + 16777216;            // [4096][6144]
  u16* Vtb  = QKVb + 25165824;            // [16*128][2048]
  u16* Ob   = Vtb  + 4194304;             // [4096][4096]

  cvt_f32_bf16<<<8192, 256, 0, stream>>>(hidden, hb, 16777216);
  cvt_f32_bf16<<<8192, 256, 0, stream>>>(Wq, wqb, 16777216);
  cvt_f32_bf16<<<2048, 256, 0, stream>>>(Wk, wkb, 4194304);
  cvt_f32_bf16<<<2048, 256, 0, stream>>>(Wv, wvb, 4194304);
  cvt_f32_bf16<<<8192, 256, 0, stream>>>(Wo, wob, 16777216);

  gemm256<1><<<384, 512, 0, stream>>>(hb, wqb, QKVb, 4096, QKV_N, 4096);  // fused QKV

  rope_kernel<<<8192, 256, 0, stream>>>(QKVb, pos, 4096, QKV_N, 0.08838834764831845f); // Q (pre-scaled)
  rope_kernel<<<2048, 256, 0, stream>>>(QKVb + 4096, pos, 1024, QKV_N, 1.0f);          // K

  transpose_v<<<512, 256, 0, stream>>>(QKVb + 5120, Vtb);

  attn_kernel<<<2048, 256, 0, stream>>>(QKVb, QKVb + 4096, Vtb, Ob);

  gemm256<0><<<256, 512, 0, stream>>>(Ob, wob, out, 4096, 4096, 4096);
}

// Round 5
// 585.980 us; speedup vs baseline: 1.0667x; 1.0667x over previous
//
#include <hip/hip_runtime.h>

#define S_LEN 2048
#define BATCH 2
#define HID 4096
#define NH 32
#define NKV 8
#define DH 128
#define MROWS (BATCH*S_LEN)   // 4096
#define QKV_N 6144

typedef unsigned short u16;
typedef unsigned int u32;
typedef __bf16 bf16x8 __attribute__((ext_vector_type(8)));
typedef float f32x4 __attribute__((ext_vector_type(4)));
typedef u16 u16x8 __attribute__((ext_vector_type(8)));

__device__ __forceinline__ u16 f2bf(float f) {           // round-half-up (2 insts)
  union { float f; u32 u; } v; v.f = f;
  return (u16)((v.u + 0x8000u) >> 16);
}
__device__ __forceinline__ float bf2f(u16 h) {
  union { u32 u; float f; } v; v.u = ((u32)h) << 16;
  return v.f;
}
__device__ __forceinline__ u32 cvtpk(float a, float b) { // packs bf16(a)|bf16(b)<<16
  u32 r;
  asm("v_cvt_pk_bf16_f32 %0, %1, %2" : "=v"(r) : "v"(a), "v"(b));
  return r;
}
__device__ __forceinline__ void async16(const void* g, void* l) {
  __builtin_amdgcn_global_load_lds(
      (const __attribute__((address_space(1))) u32*)g,
      (__attribute__((address_space(3))) u32*)l, 16, 0, 0);
}
__device__ __forceinline__ f32x4 mfma16(bf16x8 a, bf16x8 b, f32x4 c) {
  return __builtin_amdgcn_mfma_f32_16x16x32_bf16(a, b, c, 0, 0, 0);
}

// ---------------- fp32 -> bf16 conversion ----------------
__global__ __launch_bounds__(256) void cvt_f32_bf16(const float* __restrict__ in,
                                                    u16* __restrict__ out, int n) {
  int i0 = (blockIdx.x * 256 + threadIdx.x) * 8;
  if (i0 >= n) return;
  float4 a = *(const float4*)(in + i0);
  float4 b = *(const float4*)(in + i0 + 4);
  u16x8 r;
  r[0]=f2bf(a.x); r[1]=f2bf(a.y); r[2]=f2bf(a.z); r[3]=f2bf(a.w);
  r[4]=f2bf(b.x); r[5]=f2bf(b.y); r[6]=f2bf(b.z); r[7]=f2bf(b.w);
  *(u16x8*)(out + i0) = r;
}

// ---------------- 256x256 8-phase NT bf16 GEMM: C[M,N] = A[M,K] * B[N,K]^T ----
// 512 thr = 8 waves (2M x 4N); BK=64; per-wave C = 128x64 (8x4 frags 16x16).
// LDS 128KB: [dbuf2][half2][128x64] per matrix.
// Bank-conflict fix (r5): FULL 3-bit chunk swizzle, chunk ^= row&7 — fragment
// reads then span all 8 16B-slots (8 lanes/slot = conflict-free floor for
// wave64 b128). Inverse permutation on the global staging source, LDS linear.
// Per phase: {ds_read subtile | stage 1 half-tile -> barrier -> MFMA(16) -> barrier},
// counted vmcnt(4) once per K-tile.
// Stage schedule for K-tile k (buf c=k&1):  P1: (k+1).A0  P2: (k+1).A1
//                                           P3: (k+2).B0  P4: (k+2).B1 + vmcnt(4)
template<int OUT_BF16>
__global__ __launch_bounds__(512, 2) void gemm256(
    const u16* __restrict__ A, const u16* __restrict__ B, void* __restrict__ Cout,
    int M, int N, int K) {
  __shared__ u16 As[2][2][64 * 128];   // [dbuf][half][128 rows x 64 cols]
  __shared__ u16 Bs[2][2][64 * 128];
  const int NKT = K >> 6;              // K-tiles of 64 (requires NKT >= 2)
  int nTN = N >> 8;
  int nwg = gridDim.x;
  int id = ((int)blockIdx.x & 7) * (nwg >> 3) + ((int)blockIdx.x >> 3); // XCD swizzle
  int tm = id / nTN, tn = id % nTN;
  int m0 = tm << 8, n0 = tn << 8;
  int t = threadIdx.x;
  int w = t >> 6, lane = t & 63, lo = lane & 15, hi = lane >> 4;
  int wm = w >> 2, wn = w & 3;
  int rbb = (wn & 1) << 6;

  // staging geometry: thread covers 16B chunk; row = c2*64 + w*8 + lane/8
  int srow = (w << 3) + (lane >> 3);
  int scol = (lane & 7) << 3;          // u16 col base of 8-elem chunk

  auto stageA = [&](int kt, int buf, int h) {
#pragma unroll
    for (int c2 = 0; c2 < 2; ++c2) {
      int row = (c2 << 6) + srow;
      int col = scol ^ ((row & 7) << 3);          // inverse swizzle on source
      async16(A + (size_t)(m0 + (h << 7) + row) * K + (kt << 6) + col,
              (char*)&As[buf][h][0] + (c2 << 13) + (w << 10));
    }
  };
  auto stageB = [&](int kt, int buf, int h) {
#pragma unroll
    for (int c2 = 0; c2 < 2; ++c2) {
      int row = (c2 << 6) + srow;
      int col = scol ^ ((row & 7) << 3);
      async16(B + (size_t)(n0 + (h << 7) + row) * K + (kt << 6) + col,
              (char*)&Bs[buf][h][0] + (c2 << 13) + (w << 10));
    }
  };

  const f32x4 fz = {0.f, 0.f, 0.f, 0.f};
  f32x4 acc[8][4];
#pragma unroll
  for (int i = 0; i < 8; ++i)
#pragma unroll
    for (int j = 0; j < 4; ++j) acc[i][j] = fz;
  bf16x8 af[4][2], bfr[4][2];

  // prologue: k0 complete (8 loads) + k1.B (4 loads); wait first 8, keep 4 in flight
  stageB(0, 0, 0); stageB(0, 0, 1);
  stageA(0, 0, 0); stageA(0, 0, 1);
  stageB(1, 1, 0); stageB(1, 1, 1);
  asm volatile("s_waitcnt vmcnt(4)" ::: "memory");
  __builtin_amdgcn_s_barrier();

  for (int kt = 0; kt < NKT; ++kt) {
    int c = kt & 1;
    const u16* Ab = &As[c][wm][0];
    const u16* Bb = &Bs[c][wn >> 1][0];
    int kn1 = (kt + 1 == NKT) ? 0 : kt + 1;            // wrap: redundant but uniform
    int kn2 = (kt + 2 >= NKT) ? kt + 2 - NKT : kt + 2;

    // ---- P1: read A(Mf0-3) + B(Nf0-1); stage (k+1).A0; MFMA Q(0,0)
#pragma unroll
    for (int mf = 0; mf < 4; ++mf)
#pragma unroll
      for (int ks = 0; ks < 2; ++ks) {
        int ra = (mf << 4) + lo;
        af[mf][ks] = *(const bf16x8*)(Ab + (ra << 6) +
                      (((ks << 5) + (hi << 3)) ^ ((ra & 7) << 3)));
      }
#pragma unroll
    for (int nf = 0; nf < 2; ++nf)
#pragma unroll
      for (int ks = 0; ks < 2; ++ks) {
        int rb = rbb + (nf << 4) + lo;
        bfr[nf][ks] = *(const bf16x8*)(Bb + (rb << 6) +
                      (((ks << 5) + (hi << 3)) ^ ((rb & 7) << 3)));
      }
    stageA(kn1, c ^ 1, 0);
    __builtin_amdgcn_s_barrier();
    __builtin_amdgcn_s_setprio(1);
#pragma unroll
    for (int mf = 0; mf < 4; ++mf)
#pragma unroll
      for (int nf = 0; nf < 2; ++nf)
#pragma unroll
        for (int ks = 0; ks < 2; ++ks)
          acc[mf][nf] = mfma16(af[mf][ks], bfr[nf][ks], acc[mf][nf]);
    __builtin_amdgcn_s_setprio(0);
    __builtin_amdgcn_s_barrier();

    // ---- P2: read B(Nf2-3); stage (k+1).A1; MFMA Q(0,1)
#pragma unroll
    for (int nf = 0; nf < 2; ++nf)
#pragma unroll
      for (int ks = 0; ks < 2; ++ks) {
        int rb = rbb + ((nf + 2) << 4) + lo;
        bfr[nf + 2][ks] = *(const bf16x8*)(Bb + (rb << 6) +
                      (((ks << 5) + (hi << 3)) ^ ((rb & 7) << 3)));
      }
    stageA(kn1, c ^ 1, 1);
    __builtin_amdgcn_s_barrier();
    __builtin_amdgcn_s_setprio(1);
#pragma unroll
    for (int mf = 0; mf < 4; ++mf)
#pragma unroll
      for (int nf = 0; nf < 2; ++nf)
#pragma unroll
        for (int ks = 0; ks < 2; ++ks)
          acc[mf][nf + 2] = mfma16(af[mf][ks], bfr[nf + 2][ks], acc[mf][nf + 2]);
    __builtin_amdgcn_s_setprio(0);
    __builtin_amdgcn_s_barrier();

    // ---- P3: read A(Mf4-7); stage (k+2).B0; MFMA Q(1,1)
#pragma unroll
    for (int mf = 0; mf < 4; ++mf)
#pragma unroll
      for (int ks = 0; ks < 2; ++ks) {
        int ra = 64 + (mf << 4) + lo;
        af[mf][ks] = *(const bf16x8*)(Ab + (ra << 6) +
                      (((ks << 5) + (hi << 3)) ^ ((ra & 7) << 3)));
      }
    stageB(kn2, c, 0);
    __builtin_amdgcn_s_barrier();
    __builtin_amdgcn_s_setprio(1);
#pragma unroll
    for (int mf = 0; mf < 4; ++mf)
#pragma unroll
      for (int nf = 0; nf < 2; ++nf)
#pragma unroll
        for (int ks = 0; ks < 2; ++ks)
          acc[mf + 4][nf + 2] = mfma16(af[mf][ks], bfr[nf + 2][ks], acc[mf + 4][nf + 2]);
    __builtin_amdgcn_s_setprio(0);
    __builtin_amdgcn_s_barrier();

    // ---- P4: stage (k+2).B1; MFMA Q(1,0); vmcnt(4) once per K-tile
    stageB(kn2, c, 1);
    __builtin_amdgcn_s_barrier();
    __builtin_amdgcn_s_setprio(1);
#pragma unroll
    for (int mf = 0; mf < 4; ++mf)
#pragma unroll
      for (int nf = 0; nf < 2; ++nf)
#pragma unroll
        for (int ks = 0; ks < 2; ++ks)
          acc[mf + 4][nf] = mfma16(af[mf][ks], bfr[nf][ks], acc[mf + 4][nf]);
    __builtin_amdgcn_s_setprio(0);
    asm volatile("s_waitcnt vmcnt(4)" ::: "memory");
    __builtin_amdgcn_s_barrier();
  }

  // epilogue
#pragma unroll
  for (int mf = 0; mf < 8; ++mf)
#pragma unroll
    for (int nf = 0; nf < 4; ++nf)
#pragma unroll
      for (int r = 0; r < 4; ++r) {
        int row = m0 + (wm << 7) + (mf << 4) + (hi << 2) + r;
        int col = n0 + (wn << 6) + (nf << 4) + lo;
        if (OUT_BF16) ((u16*)Cout)[(size_t)row * N + col] = f2bf(acc[mf][nf][r]);
        else          ((float*)Cout)[(size_t)row * N + col] = acc[mf][nf][r];
      }
}

// ---------------- RoPE (in-place on bf16, optional output scale) ----------------
__global__ __launch_bounds__(256) void rope_kernel(u16* __restrict__ X,
                                                   const int* __restrict__ pos,
                                                   int ncols, int pitch, float scale) {
  int idx = blockIdx.x * 256 + threadIdx.x;
  int groups = ncols >> 3;
  int m = idx / groups;
  int gi = idx - m * groups;
  if (m >= MROWS) return;
  int head = gi >> 4;
  int d0 = (gi & 15) << 2;
  float p = (float)pos[m];
  u16* base = X + (size_t)m * pitch + head * 128;
  u16 xa[4], xb[4], oa[4], ob[4];
  *(uint2*)xa = *(const uint2*)(base + d0);
  *(uint2*)xb = *(const uint2*)(base + d0 + 64);
#pragma unroll
  for (int i = 0; i < 4; ++i) {
    float j = (float)(d0 + i);
    float inv = __expf(j * -0.14391156516030342f);  // ln(10000)/64
    float fr = p * inv;
    float s, c;
    sincosf(fr, &s, &c);
    float x1 = bf2f(xa[i]), x2 = bf2f(xb[i]);
    oa[i] = f2bf((x1 * c - x2 * s) * scale);
    ob[i] = f2bf((x2 * c + x1 * s) * scale);
  }
  *(uint2*)(base + d0) = *(uint2*)oa;
  *(uint2*)(base + d0 + 64) = *(uint2*)ob;
}

// ---------------- V transpose: QKV[m][5120 + g*128 + d] -> Vt[(b*8+g)*128 + d][s] ----------------
__global__ __launch_bounds__(256) void transpose_v(const u16* __restrict__ V,
                                                   u16* __restrict__ Vt) {
  int bid = blockIdx.x;
  int s0 = (bid & 31) << 6;
  int bg = bid >> 5;
  int b = bg >> 3, g = bg & 7;
  __shared__ u16 tile[64][128];
  int t = threadIdx.x;
#pragma unroll
  for (int r = 0; r < 4; ++r) {
    int c = (r << 8) + t;
    int row = c >> 4, cc = c & 15;
    *(uint4*)&tile[row][cc * 8] =
        *(const uint4*)(V + (size_t)(b * S_LEN + s0 + row) * QKV_N + g * 128 + cc * 8);
  }
  __syncthreads();
#pragma unroll
  for (int r = 0; r < 4; ++r) {
    int c = (r << 8) + t;
    int d = c >> 3, cs = c & 7;
    u16 tmp[8];
#pragma unroll
    for (int i = 0; i < 8; ++i) tmp[i] = tile[cs * 8 + i][d];
    *(uint4*)(Vt + ((size_t)bg * 128 + d) * S_LEN + s0 + cs * 8) = *(uint4*)tmp;
  }
}

// ---------------- Flash attention (causal, GQA 4:1), swapped-operand layout ----------------
__global__ __launch_bounds__(256) void attn_kernel(
    const u16* __restrict__ Q, const u16* __restrict__ K,
    const u16* __restrict__ Vt, u16* __restrict__ O) {
  int bid = blockIdx.x;
  int qt = 31 - (bid >> 6);          // heavy tiles first
  int bh = bid & 63;
  int b = bh >> 5, h = bh & 31;
  int g = h >> 2;
  __shared__ u16 Kl[64 * 128];
  __shared__ u16 Vl[128 * 64];
  __shared__ u16 Pl[4][16 * 72];     // per-wave P^T / O-bounce, pitch 72
  int t = threadIdx.x, w = t >> 6, lane = t & 63, lo = lane & 15, hi = lane >> 4;

  bf16x8 qf[4];   // B-operand: lane -> Q row (q=lo)
  {
    const u16* qb = Q + (size_t)(b * S_LEN + (qt << 6) + (w << 4) + lo) * QKV_N + h * 128;
#pragma unroll
    for (int kk = 0; kk < 4; ++kk) qf[kk] = *(const bf16x8*)(qb + kk * 32 + hi * 8);
  }
  const f32x4 fz = {0.f, 0.f, 0.f, 0.f};
  f32x4 acc[8];
#pragma unroll
  for (int f = 0; f < 8; ++f) acc[f] = fz;
  float mrun = -1e30f, lrun = 0.f;

  const u16* Kbase = K + (size_t)(b * S_LEN) * QKV_N + g * 128;
  const u16* Vbase = Vt + (size_t)((b << 3) + g) * 128 * S_LEN;

  int ntiles = qt + 1;
  for (int tile = 0; tile < ntiles; ++tile) {
    int s0 = tile << 6;
#pragma unroll
    for (int r = 0; r < 4; ++r) {              // stage K tile [64][128], chunk-swizzled
      int c = (r << 8) + (w << 6) + lane;
      int row = c >> 4, cc = c & 15;
      int src = cc ^ (row & 7);
      async16(Kbase + (size_t)(s0 + row) * QKV_N + src * 8,
              (char*)Kl + (r << 12) + (w << 10));
    }
#pragma unroll
    for (int r = 0; r < 4; ++r) {              // stage V^T tile [128][64], chunk-swizzled
      int c = (r << 8) + (w << 6) + lane;
      int row = c >> 3, cc = c & 7;
      int src = cc ^ (row & 7);
      async16(Vbase + (size_t)row * S_LEN + s0 + src * 8,
              (char*)Vl + (r << 12) + (w << 10));
    }
    __syncthreads();

    f32x4 sf[4];
#pragma unroll
    for (int j = 0; j < 4; ++j) {
      f32x4 sv = fz;
#pragma unroll
      for (int kk = 0; kk < 4; ++kk) {
        int row = (j << 4) + lo;
        int ch = ((kk << 2) + hi) ^ (row & 7);
        bf16x8 kf = *(const bf16x8*)(Kl + row * 128 + ch * 8);
        sv = __builtin_amdgcn_mfma_f32_16x16x32_bf16(kf, qf[kk], sv, 0, 0, 0);
      }
      sf[j] = sv;
    }
    if (tile == qt) {                           // causal mask on diagonal tile
      int q_rel = (w << 4) + lo;
#pragma unroll
      for (int j = 0; j < 4; ++j)
#pragma unroll
        for (int r = 0; r < 4; ++r)
          if (((j << 4) + (hi << 2) + r) > q_rel) sf[j][r] = -1e9f;
    }
    float pmax = sf[0][0];
#pragma unroll
    for (int j = 0; j < 4; ++j)
#pragma unroll
      for (int r = 0; r < 4; ++r) pmax = fmaxf(pmax, sf[j][r]);
    pmax = fmaxf(pmax, __shfl_xor(pmax, 16, 64));
    pmax = fmaxf(pmax, __shfl_xor(pmax, 32, 64));
    if (__any(pmax > mrun + 8.f)) {             // defer-max rescale (THR=8)
      float mn = fmaxf(mrun, pmax);
      float fsc = __expf(mrun - mn);
      mrun = mn;
      lrun *= fsc;
#pragma unroll
      for (int f = 0; f < 8; ++f)
#pragma unroll
        for (int r = 0; r < 4; ++r) acc[f][r] *= fsc;
    }
    float psum = 0.f;
#pragma unroll
    for (int j = 0; j < 4; ++j)
#pragma unroll
      for (int r = 0; r < 4; ++r) {
        float p = __expf(sf[j][r] - mrun);
        sf[j][r] = p;
        psum += p;
      }
    psum += __shfl_xor(psum, 16, 64);
    psum += __shfl_xor(psum, 32, 64);
    lrun += psum;

#pragma unroll
    for (int j = 0; j < 4; ++j) {
      uint2 pk;
      pk.x = cvtpk(sf[j][0], sf[j][1]);
      pk.y = cvtpk(sf[j][2], sf[j][3]);
      *(uint2*)&Pl[w][lo * 72 + (j << 4) + (hi << 2)] = pk;
    }
#pragma unroll
    for (int kk = 0; kk < 2; ++kk) {
      bf16x8 pf = *(const bf16x8*)&Pl[w][lo * 72 + (kk << 5) + (hi << 3)];
#pragma unroll
      for (int f = 0; f < 8; ++f) {
        int vrow = (f << 4) + lo;
        int phys = ((kk << 2) + hi) ^ (vrow & 7);
        bf16x8 vf = *(const bf16x8*)(Vl + vrow * 64 + phys * 8);
        acc[f] = __builtin_amdgcn_mfma_f32_16x16x32_bf16(vf, pf, acc[f], 0, 0, 0);
      }
    }
    __syncthreads();
  }

  float rl = 1.0f / lrun;
#pragma unroll
  for (int half = 0; half < 2; ++half) {
#pragma unroll
    for (int f2 = 0; f2 < 4; ++f2) {
      int f = (half << 2) + f2;
      uint2 pk;
      pk.x = cvtpk(acc[f][0] * rl, acc[f][1] * rl);
      pk.y = cvtpk(acc[f][2] * rl, acc[f][3] * rl);
      *(uint2*)&Pl[w][lo * 72 + (f2 << 4) + (hi << 2)] = pk;
    }
#pragma unroll
    for (int it = 0; it < 2; ++it) {
      int rowq = (lane >> 3) + (it << 3);
      int c8 = lane & 7;
      uint4 val = *(const uint4*)&Pl[w][rowq * 72 + c8 * 8];
      *(uint4*)(O + (size_t)(b * S_LEN + (qt << 6) + (w << 4) + rowq) * 4096 +
                h * 128 + (half << 6) + c8 * 8) = val;
    }
  }
}

// ---------------- launch ----------------
extern "C" void kernel_launch(void* const* d_in, const int* in_sizes, int n_in,
                              void* d_out, int out_size, void* d_ws, size_t ws_size,
                              hipStream_t stream) {
  const float* hidden = (const float*)d_in[0];
  const int* pos = (const int*)d_in[1];
  const float* Wq = (const float*)d_in[2];
  const float* Wk = (const float*)d_in[3];
  const float* Wv = (const float*)d_in[4];
  const float* Wo = (const float*)d_in[5];
  float* out = (float*)d_out;

  u16* hb   = (u16*)d_ws;                 // [4096][4096]
  u16* wqb  = hb   + 16777216;            // [4096][4096]  } contiguous -> fused
  u16* wkb  = wqb  + 16777216;            // [1024][4096]  }   B matrix [6144][4096]
  u16* wvb  = wkb  + 4194304;             // [1024][4096]  }
  u16* wob  = wvb  + 4194304;             // [4096][4096]
  u16* QKVb = wob  + 16777216;            // [4096][6144]
  u16* Vtb  = QKVb + 25165824;            // [16*128][2048]
  u16* Ob   = Vtb  + 4194304;             // [4096][4096]

  cvt_f32_bf16<<<8192, 256, 0, stream>>>(hidden, hb, 16777216);
  cvt_f32_bf16<<<8192, 256, 0, stream>>>(Wq, wqb, 16777216);
  cvt_f32_bf16<<<2048, 256, 0, stream>>>(Wk, wkb, 4194304);
  cvt_f32_bf16<<<2048, 256, 0, stream>>>(Wv, wvb, 4194304);
  cvt_f32_bf16<<<8192, 256, 0, stream>>>(Wo, wob, 16777216);

  gemm256<1><<<384, 512, 0, stream>>>(hb, wqb, QKVb, 4096, QKV_N, 4096);  // fused QKV

  rope_kernel<<<8192, 256, 0, stream>>>(QKVb, pos, 4096, QKV_N, 0.08838834764831845f); // Q (pre-scaled)
  rope_kernel<<<2048, 256, 0, stream>>>(QKVb + 4096, pos, 1024, QKV_N, 1.0f);          // K

  transpose_v<<<512, 256, 0, stream>>>(QKVb + 5120, Vtb);

  attn_kernel<<<2048, 256, 0, stream>>>(QKVb, QKVb + 4096, Vtb, Ob);

  gemm256<0><<<256, 512, 0, stream>>>(Ob, wob, out, 4096, 4096, 4096);
}

// Round 6
// 543.973 us; speedup vs baseline: 1.1491x; 1.0772x over previous
//
#include <hip/hip_runtime.h>

#define S_LEN 2048
#define BATCH 2
#define HID 4096
#define NH 32
#define NKV 8
#define DH 128
#define MROWS (BATCH*S_LEN)   // 4096
#define QKV_N 6144

typedef unsigned short u16;
typedef unsigned int u32;
typedef __bf16 bf16x8 __attribute__((ext_vector_type(8)));
typedef float f32x4 __attribute__((ext_vector_type(4)));
typedef u16 u16x8 __attribute__((ext_vector_type(8)));

__device__ __forceinline__ u16 f2bf(float f) {           // round-half-up (2 insts)
  union { float f; u32 u; } v; v.f = f;
  return (u16)((v.u + 0x8000u) >> 16);
}
__device__ __forceinline__ float bf2f(u16 h) {
  union { u32 u; float f; } v; v.u = ((u32)h) << 16;
  return v.f;
}
__device__ __forceinline__ u32 cvtpk(float a, float b) { // packs bf16(a)|bf16(b)<<16
  u32 r;
  asm("v_cvt_pk_bf16_f32 %0, %1, %2" : "=v"(r) : "v"(a), "v"(b));
  return r;
}
__device__ __forceinline__ void async16(const void* g, void* l) {
  __builtin_amdgcn_global_load_lds(
      (const __attribute__((address_space(1))) u32*)g,
      (__attribute__((address_space(3))) u32*)l, 16, 0, 0);
}
__device__ __forceinline__ f32x4 mfma16(bf16x8 a, bf16x8 b, f32x4 c) {
  return __builtin_amdgcn_mfma_f32_16x16x32_bf16(a, b, c, 0, 0, 0);
}

// ---------------- fp32 -> bf16 conversion ----------------
__global__ __launch_bounds__(256) void cvt_f32_bf16(const float* __restrict__ in,
                                                    u16* __restrict__ out, int n) {
  int i0 = (blockIdx.x * 256 + threadIdx.x) * 8;
  if (i0 >= n) return;
  float4 a = *(const float4*)(in + i0);
  float4 b = *(const float4*)(in + i0 + 4);
  u16x8 r;
  r[0]=f2bf(a.x); r[1]=f2bf(a.y); r[2]=f2bf(a.z); r[3]=f2bf(a.w);
  r[4]=f2bf(b.x); r[5]=f2bf(b.y); r[6]=f2bf(b.z); r[7]=f2bf(b.w);
  *(u16x8*)(out + i0) = r;
}

// ---------------- 256x256 NT bf16 GEMM with READ-AHEAD phases --------------
// 512 thr = 8 waves (2M x 4N); BK=64; per-wave C = 128x64 (8x4 frags 16x16).
// LDS 128KB [dbuf2][half2][128x64] per matrix; 3-bit chunk swizzle (conflict-free, r5).
// r6: ds_reads no longer feed their own phase's MFMA (that serialized LDS-port
// time with MFMA under lockstep barriers ~ 4600cy/K-tile). Every fragment is
// read >=1 phase ahead, mostly in post-MFMA slots, so LDS reads overlap a
// non-dependent MFMA cluster:
//   P1: rdB1(k) pre-MFMA      | stage A(k+1) h0,h1 | MFMA Q00(A0,B0)
//   P2:                        |                    | MFMA Q01(A0,B1); rdA1(k) post; vmcnt(0)
//   P3:                        | stage B(k+2) h0    | MFMA Q11(A1,B1)
//   P4:                        | stage B(k+2) h1    | MFMA Q10(A1,B0); rdA0(k+1)+rdB0(k+1) post
// vmcnt(0)@P2-end + barrier: A(k+1) (1 phase old) and B(k+1) (5 phases old)
// landed for ALL waves before any P4 read of buf c^1. Every staged region is
// >=1 barrier past its last read's forced drain (checked per region).
template<int OUT_BF16>
__global__ __launch_bounds__(512, 2) void gemm256(
    const u16* __restrict__ A, const u16* __restrict__ B, void* __restrict__ Cout,
    int M, int N, int K) {
  __shared__ u16 As[2][2][64 * 128];   // [dbuf][half][128 rows x 64 cols]
  __shared__ u16 Bs[2][2][64 * 128];
  const int NKT = K >> 6;              // K-tiles of 64 (requires NKT >= 3)
  int nTN = N >> 8;
  int nwg = gridDim.x;
  int id = ((int)blockIdx.x & 7) * (nwg >> 3) + ((int)blockIdx.x >> 3); // XCD swizzle
  int tm = id / nTN, tn = id % nTN;
  int m0 = tm << 8, n0 = tn << 8;
  int t = threadIdx.x;
  int w = t >> 6, lane = t & 63, lo = lane & 15, hi = lane >> 4;
  int wm = w >> 2, wn = w & 3;
  int rbb = (wn & 1) << 6;

  // staging geometry: thread covers 16B chunk; row = c2*64 + w*8 + lane/8
  int srow = (w << 3) + (lane >> 3);
  int scol = (lane & 7) << 3;          // u16 col base of 8-elem chunk

  auto stageA = [&](int kt, int buf, int h) {
#pragma unroll
    for (int c2 = 0; c2 < 2; ++c2) {
      int row = (c2 << 6) + srow;
      int col = scol ^ ((row & 7) << 3);          // inverse swizzle on source
      async16(A + (size_t)(m0 + (h << 7) + row) * K + (kt << 6) + col,
              (char*)&As[buf][h][0] + (c2 << 13) + (w << 10));
    }
  };
  auto stageB = [&](int kt, int buf, int h) {
#pragma unroll
    for (int c2 = 0; c2 < 2; ++c2) {
      int row = (c2 << 6) + srow;
      int col = scol ^ ((row & 7) << 3);
      async16(B + (size_t)(n0 + (h << 7) + row) * K + (kt << 6) + col,
              (char*)&Bs[buf][h][0] + (c2 << 13) + (w << 10));
    }
  };

  const f32x4 fz = {0.f, 0.f, 0.f, 0.f};
  f32x4 acc[8][4];
#pragma unroll
  for (int i = 0; i < 8; ++i)
#pragma unroll
    for (int j = 0; j < 4; ++j) acc[i][j] = fz;
  bf16x8 af[4][2], bf0[2][2], bf1[2][2];

  auto rdA = [&](int c, int half, bf16x8 (&dst)[4][2]) {   // 8 x ds_read_b128
    const u16* Ab = &As[c][wm][0];
#pragma unroll
    for (int mf = 0; mf < 4; ++mf)
#pragma unroll
      for (int ks = 0; ks < 2; ++ks) {
        int ra = (half << 6) + (mf << 4) + lo;
        dst[mf][ks] = *(const bf16x8*)(Ab + (ra << 6) +
                      (((ks << 5) + (hi << 3)) ^ ((ra & 7) << 3)));
      }
  };
  auto rdB = [&](int c, int bfrag, bf16x8 (&dst)[2][2]) {  // 4 x ds_read_b128
    const u16* Bb = &Bs[c][wn >> 1][0];
#pragma unroll
    for (int nf = 0; nf < 2; ++nf)
#pragma unroll
      for (int ks = 0; ks < 2; ++ks) {
        int rb = rbb + (bfrag << 5) + (nf << 4) + lo;
        dst[nf][ks] = *(const bf16x8*)(Bb + (rb << 6) +
                      (((ks << 5) + (hi << 3)) ^ ((rb & 7) << 3)));
      }
  };
  auto MM = [&](bf16x8 (&a)[4][2], bf16x8 (&b)[2][2], int mo, int no) {
#pragma unroll
    for (int mf = 0; mf < 4; ++mf)
#pragma unroll
      for (int nf = 0; nf < 2; ++nf)
#pragma unroll
        for (int ks = 0; ks < 2; ++ks)
          acc[mo + mf][no + nf] = mfma16(a[mf][ks], b[nf][ks], acc[mo + mf][no + nf]);
  };

  // prologue: tile0 (A+B, 8 loads) + tile1 B (4 loads); drain tile0, keep B(1) flying
  stageA(0, 0, 0); stageA(0, 0, 1);
  stageB(0, 0, 0); stageB(0, 0, 1);
  stageB(1, 1, 0); stageB(1, 1, 1);
  asm volatile("s_waitcnt vmcnt(4)" ::: "memory");
  __builtin_amdgcn_s_barrier();
  rdA(0, 0, af);      // A0(0)
  rdB(0, 0, bf0);     // B0(0)

  for (int kt = 0; kt < NKT; ++kt) {
    int c = kt & 1;
    int kn1 = (kt + 1 == NKT) ? 0 : kt + 1;            // wrap: redundant but uniform
    int kn2 = (kt + 2 >= NKT) ? kt + 2 - NKT : kt + 2;

    // ---- P1: read B1(k) (feeds P2); stage A(k+1) both halves; MFMA Q00
    rdB(c, 1, bf1);
    stageA(kn1, c ^ 1, 0); stageA(kn1, c ^ 1, 1);
    __builtin_amdgcn_s_barrier();
    __builtin_amdgcn_s_setprio(1);
    MM(af, bf0, 0, 0);
    __builtin_amdgcn_s_setprio(0);
    __builtin_amdgcn_s_barrier();

    // ---- P2: MFMA Q01; post-MFMA read A1(k) (feeds P3); vmcnt(0) drains A(k+1),B(k+1)
    __builtin_amdgcn_s_setprio(1);
    MM(af, bf1, 0, 2);
    __builtin_amdgcn_s_setprio(0);
    rdA(c, 1, af);
    asm volatile("s_waitcnt vmcnt(0)" ::: "memory");
    __builtin_amdgcn_s_barrier();

    // ---- P3: stage B0(k+2); MFMA Q11
    stageB(kn2, c, 0);
    __builtin_amdgcn_s_barrier();
    __builtin_amdgcn_s_setprio(1);
    MM(af, bf1, 4, 2);
    __builtin_amdgcn_s_setprio(0);
    __builtin_amdgcn_s_barrier();

    // ---- P4: stage B1(k+2); MFMA Q10; post-MFMA read A0(k+1)+B0(k+1) (feed next P1)
    stageB(kn2, c, 1);
    __builtin_amdgcn_s_barrier();
    __builtin_amdgcn_s_setprio(1);
    MM(af, bf0, 4, 0);
    __builtin_amdgcn_s_setprio(0);
    rdA(c ^ 1, 0, af);
    rdB(c ^ 1, 0, bf0);
    __builtin_amdgcn_s_barrier();
  }

  // epilogue
#pragma unroll
  for (int mf = 0; mf < 8; ++mf)
#pragma unroll
    for (int nf = 0; nf < 4; ++nf)
#pragma unroll
      for (int r = 0; r < 4; ++r) {
        int row = m0 + (wm << 7) + (mf << 4) + (hi << 2) + r;
        int col = n0 + (wn << 6) + (nf << 4) + lo;
        if (OUT_BF16) ((u16*)Cout)[(size_t)row * N + col] = f2bf(acc[mf][nf][r]);
        else          ((float*)Cout)[(size_t)row * N + col] = acc[mf][nf][r];
      }
}

// ---------------- RoPE (in-place on bf16, optional output scale) ----------------
__global__ __launch_bounds__(256) void rope_kernel(u16* __restrict__ X,
                                                   const int* __restrict__ pos,
                                                   int ncols, int pitch, float scale) {
  int idx = blockIdx.x * 256 + threadIdx.x;
  int groups = ncols >> 3;
  int m = idx / groups;
  int gi = idx - m * groups;
  if (m >= MROWS) return;
  int head = gi >> 4;
  int d0 = (gi & 15) << 2;
  float p = (float)pos[m];
  u16* base = X + (size_t)m * pitch + head * 128;
  u16 xa[4], xb[4], oa[4], ob[4];
  *(uint2*)xa = *(const uint2*)(base + d0);
  *(uint2*)xb = *(const uint2*)(base + d0 + 64);
#pragma unroll
  for (int i = 0; i < 4; ++i) {
    float j = (float)(d0 + i);
    float inv = __expf(j * -0.14391156516030342f);  // ln(10000)/64
    float fr = p * inv;
    float s, c;
    sincosf(fr, &s, &c);
    float x1 = bf2f(xa[i]), x2 = bf2f(xb[i]);
    oa[i] = f2bf((x1 * c - x2 * s) * scale);
    ob[i] = f2bf((x2 * c + x1 * s) * scale);
  }
  *(uint2*)(base + d0) = *(uint2*)oa;
  *(uint2*)(base + d0 + 64) = *(uint2*)ob;
}

// ---------------- V transpose: QKV[m][5120 + g*128 + d] -> Vt[(b*8+g)*128 + d][s] ----------------
__global__ __launch_bounds__(256) void transpose_v(const u16* __restrict__ V,
                                                   u16* __restrict__ Vt) {
  int bid = blockIdx.x;
  int s0 = (bid & 31) << 6;
  int bg = bid >> 5;
  int b = bg >> 3, g = bg & 7;
  __shared__ u16 tile[64][128];
  int t = threadIdx.x;
#pragma unroll
  for (int r = 0; r < 4; ++r) {
    int c = (r << 8) + t;
    int row = c >> 4, cc = c & 15;
    *(uint4*)&tile[row][cc * 8] =
        *(const uint4*)(V + (size_t)(b * S_LEN + s0 + row) * QKV_N + g * 128 + cc * 8);
  }
  __syncthreads();
#pragma unroll
  for (int r = 0; r < 4; ++r) {
    int c = (r << 8) + t;
    int d = c >> 3, cs = c & 7;
    u16 tmp[8];
#pragma unroll
    for (int i = 0; i < 8; ++i) tmp[i] = tile[cs * 8 + i][d];
    *(uint4*)(Vt + ((size_t)bg * 128 + d) * S_LEN + s0 + cs * 8) = *(uint4*)tmp;
  }
}

// ---------------- Flash attention (causal, GQA 4:1), swapped-operand layout ----------------
__global__ __launch_bounds__(256) void attn_kernel(
    const u16* __restrict__ Q, const u16* __restrict__ K,
    const u16* __restrict__ Vt, u16* __restrict__ O) {
  int bid = blockIdx.x;
  int qt = 31 - (bid >> 6);          // heavy tiles first
  int bh = bid & 63;
  int b = bh >> 5, h = bh & 31;
  int g = h >> 2;
  __shared__ u16 Kl[64 * 128];
  __shared__ u16 Vl[128 * 64];
  __shared__ u16 Pl[4][16 * 72];     // per-wave P^T / O-bounce, pitch 72
  int t = threadIdx.x, w = t >> 6, lane = t & 63, lo = lane & 15, hi = lane >> 4;

  bf16x8 qf[4];   // B-operand: lane -> Q row (q=lo)
  {
    const u16* qb = Q + (size_t)(b * S_LEN + (qt << 6) + (w << 4) + lo) * QKV_N + h * 128;
#pragma unroll
    for (int kk = 0; kk < 4; ++kk) qf[kk] = *(const bf16x8*)(qb + kk * 32 + hi * 8);
  }
  const f32x4 fz = {0.f, 0.f, 0.f, 0.f};
  f32x4 acc[8];
#pragma unroll
  for (int f = 0; f < 8; ++f) acc[f] = fz;
  float mrun = -1e30f, lrun = 0.f;

  const u16* Kbase = K + (size_t)(b * S_LEN) * QKV_N + g * 128;
  const u16* Vbase = Vt + (size_t)((b << 3) + g) * 128 * S_LEN;

  int ntiles = qt + 1;
  for (int tile = 0; tile < ntiles; ++tile) {
    int s0 = tile << 6;
#pragma unroll
    for (int r = 0; r < 4; ++r) {              // stage K tile [64][128], chunk-swizzled
      int c = (r << 8) + (w << 6) + lane;
      int row = c >> 4, cc = c & 15;
      int src = cc ^ (row & 7);
      async16(Kbase + (size_t)(s0 + row) * QKV_N + src * 8,
              (char*)Kl + (r << 12) + (w << 10));
    }
#pragma unroll
    for (int r = 0; r < 4; ++r) {              // stage V^T tile [128][64], chunk-swizzled
      int c = (r << 8) + (w << 6) + lane;
      int row = c >> 3, cc = c & 7;
      int src = cc ^ (row & 7);
      async16(Vbase + (size_t)row * S_LEN + s0 + src * 8,
              (char*)Vl + (r << 12) + (w << 10));
    }
    __syncthreads();

    f32x4 sf[4];
#pragma unroll
    for (int j = 0; j < 4; ++j) {
      f32x4 sv = fz;
#pragma unroll
      for (int kk = 0; kk < 4; ++kk) {
        int row = (j << 4) + lo;
        int ch = ((kk << 2) + hi) ^ (row & 7);
        bf16x8 kf = *(const bf16x8*)(Kl + row * 128 + ch * 8);
        sv = __builtin_amdgcn_mfma_f32_16x16x32_bf16(kf, qf[kk], sv, 0, 0, 0);
      }
      sf[j] = sv;
    }
    if (tile == qt) {                           // causal mask on diagonal tile
      int q_rel = (w << 4) + lo;
#pragma unroll
      for (int j = 0; j < 4; ++j)
#pragma unroll
        for (int r = 0; r < 4; ++r)
          if (((j << 4) + (hi << 2) + r) > q_rel) sf[j][r] = -1e9f;
    }
    float pmax = sf[0][0];
#pragma unroll
    for (int j = 0; j < 4; ++j)
#pragma unroll
      for (int r = 0; r < 4; ++r) pmax = fmaxf(pmax, sf[j][r]);
    pmax = fmaxf(pmax, __shfl_xor(pmax, 16, 64));
    pmax = fmaxf(pmax, __shfl_xor(pmax, 32, 64));
    if (__any(pmax > mrun + 8.f)) {             // defer-max rescale (THR=8)
      float mn = fmaxf(mrun, pmax);
      float fsc = __expf(mrun - mn);
      mrun = mn;
      lrun *= fsc;
#pragma unroll
      for (int f = 0; f < 8; ++f)
#pragma unroll
        for (int r = 0; r < 4; ++r) acc[f][r] *= fsc;
    }
    float psum = 0.f;
#pragma unroll
    for (int j = 0; j < 4; ++j)
#pragma unroll
      for (int r = 0; r < 4; ++r) {
        float p = __expf(sf[j][r] - mrun);
        sf[j][r] = p;
        psum += p;
      }
    psum += __shfl_xor(psum, 16, 64);
    psum += __shfl_xor(psum, 32, 64);
    lrun += psum;

#pragma unroll
    for (int j = 0; j < 4; ++j) {
      uint2 pk;
      pk.x = cvtpk(sf[j][0], sf[j][1]);
      pk.y = cvtpk(sf[j][2], sf[j][3]);
      *(uint2*)&Pl[w][lo * 72 + (j << 4) + (hi << 2)] = pk;
    }
#pragma unroll
    for (int kk = 0; kk < 2; ++kk) {
      bf16x8 pf = *(const bf16x8*)&Pl[w][lo * 72 + (kk << 5) + (hi << 3)];
#pragma unroll
      for (int f = 0; f < 8; ++f) {
        int vrow = (f << 4) + lo;
        int phys = ((kk << 2) + hi) ^ (vrow & 7);
        bf16x8 vf = *(const bf16x8*)(Vl + vrow * 64 + phys * 8);
        acc[f] = __builtin_amdgcn_mfma_f32_16x16x32_bf16(vf, pf, acc[f], 0, 0, 0);
      }
    }
    __syncthreads();
  }

  float rl = 1.0f / lrun;
#pragma unroll
  for (int half = 0; half < 2; ++half) {
#pragma unroll
    for (int f2 = 0; f2 < 4; ++f2) {
      int f = (half << 2) + f2;
      uint2 pk;
      pk.x = cvtpk(acc[f][0] * rl, acc[f][1] * rl);
      pk.y = cvtpk(acc[f][2] * rl, acc[f][3] * rl);
      *(uint2*)&Pl[w][lo * 72 + (f2 << 4) + (hi << 2)] = pk;
    }
#pragma unroll
    for (int it = 0; it < 2; ++it) {
      int rowq = (lane >> 3) + (it << 3);
      int c8 = lane & 7;
      uint4 val = *(const uint4*)&Pl[w][rowq * 72 + c8 * 8];
      *(uint4*)(O + (size_t)(b * S_LEN + (qt << 6) + (w << 4) + rowq) * 4096 +
                h * 128 + (half << 6) + c8 * 8) = val;
    }
  }
}

// ---------------- launch ----------------
extern "C" void kernel_launch(void* const* d_in, const int* in_sizes, int n_in,
                              void* d_out, int out_size, void* d_ws, size_t ws_size,
                              hipStream_t stream) {
  const float* hidden = (const float*)d_in[0];
  const int* pos = (const int*)d_in[1];
  const float* Wq = (const float*)d_in[2];
  const float* Wk = (const float*)d_in[3];
  const float* Wv = (const float*)d_in[4];
  const float* Wo = (const float*)d_in[5];
  float* out = (float*)d_out;

  u16* hb   = (u16*)d_ws;                 // [4096][4096]
  u16* wqb  = hb   + 16777216;            // [4096][4096]  } contiguous -> fused
  u16* wkb  = wqb  + 16777216;            // [1024][4096]  }   B matrix [6144][4096]
  u16* wvb  = wkb  + 4194304;             // [1024][4096]  }
  u16* wob  = wvb  + 4194304;             // [4096][4096]
  u16* QKVb = wob  + 16777216;            // [4096][6144]
  u16* Vtb  = QKVb + 25165824;            // [16*128][2048]
  u16* Ob   = Vtb  + 4194304;             // [4096][4096]

  cvt_f32_bf16<<<8192, 256, 0, stream>>>(hidden, hb, 16777216);
  cvt_f32_bf16<<<8192, 256, 0, stream>>>(Wq, wqb, 16777216);
  cvt_f32_bf16<<<2048, 256, 0, stream>>>(Wk, wkb, 4194304);
  cvt_f32_bf16<<<2048, 256, 0, stream>>>(Wv, wvb, 4194304);
  cvt_f32_bf16<<<8192, 256, 0, stream>>>(Wo, wob, 16777216);

  gemm256<1><<<384, 512, 0, stream>>>(hb, wqb, QKVb, 4096, QKV_N, 4096);  // fused QKV

  rope_kernel<<<8192, 256, 0, stream>>>(QKVb, pos, 4096, QKV_N, 0.08838834764831845f); // Q (pre-scaled)
  rope_kernel<<<2048, 256, 0, stream>>>(QKVb + 4096, pos, 1024, QKV_N, 1.0f);          // K

  transpose_v<<<512, 256, 0, stream>>>(QKVb + 5120, Vtb);

  attn_kernel<<<2048, 256, 0, stream>>>(QKVb, QKVb + 4096, Vtb, Ob);

  gemm256<0><<<256, 512, 0, stream>>>(Ob, wob, out, 4096, 4096, 4096);
}

// Round 7
// 542.544 us; speedup vs baseline: 1.1521x; 1.0026x over previous
//
#include <hip/hip_runtime.h>

#define S_LEN 2048
#define BATCH 2
#define HID 4096
#define NH 32
#define NKV 8
#define DH 128
#define MROWS (BATCH*S_LEN)   // 4096
#define QKV_N 6144

typedef unsigned short u16;
typedef unsigned int u32;
typedef __bf16 bf16x8 __attribute__((ext_vector_type(8)));
typedef float f32x4 __attribute__((ext_vector_type(4)));
typedef u16 u16x8 __attribute__((ext_vector_type(8)));

__device__ __forceinline__ u16 f2bf(float f) {           // round-half-up (2 insts)
  union { float f; u32 u; } v; v.f = f;
  return (u16)((v.u + 0x8000u) >> 16);
}
__device__ __forceinline__ float bf2f(u16 h) {
  union { u32 u; float f; } v; v.u = ((u32)h) << 16;
  return v.f;
}
__device__ __forceinline__ u32 cvtpk(float a, float b) { // packs bf16(a)|bf16(b)<<16
  u32 r;
  asm("v_cvt_pk_bf16_f32 %0, %1, %2" : "=v"(r) : "v"(a), "v"(b));
  return r;
}
__device__ __forceinline__ void async16(const void* g, void* l) {
  __builtin_amdgcn_global_load_lds(
      (const __attribute__((address_space(1))) u32*)g,
      (__attribute__((address_space(3))) u32*)l, 16, 0, 0);
}
__device__ __forceinline__ f32x4 mfma16(bf16x8 a, bf16x8 b, f32x4 c) {
  return __builtin_amdgcn_mfma_f32_16x16x32_bf16(a, b, c, 0, 0, 0);
}

// ---------------- fp32 -> bf16 conversion ----------------
__global__ __launch_bounds__(256) void cvt_f32_bf16(const float* __restrict__ in,
                                                    u16* __restrict__ out, int n) {
  int i0 = (blockIdx.x * 256 + threadIdx.x) * 8;
  if (i0 >= n) return;
  float4 a = *(const float4*)(in + i0);
  float4 b = *(const float4*)(in + i0 + 4);
  u16x8 r;
  r[0]=f2bf(a.x); r[1]=f2bf(a.y); r[2]=f2bf(a.z); r[3]=f2bf(a.w);
  r[4]=f2bf(b.x); r[5]=f2bf(b.y); r[6]=f2bf(b.z); r[7]=f2bf(b.w);
  *(u16x8*)(out + i0) = r;
}

// ---------------- 256x256 NT bf16 GEMM, read-ahead + COUNTED vmcnt (T4) ----
// 512 thr = 8 waves (2M x 4N); BK=64; per-wave C = 128x64 (8x4 frags 16x16).
// LDS 128KB [dbuf2][half2][128x64] per matrix; 3-bit chunk swizzle (conflict-free, r5).
// r7: the r6 schedule drained vmcnt(0) at P2-end — the youngest loads there
// (A(k+1), issued P1) are ~1 phase (<HBM latency) old -> all-wave stall every
// K-tile (T4 anti-pattern; m218: drain0 costs ~38%@4k). Replaced by counted
// vmcnt(2) at P3-end: outstanding = {B(k+1)h0,h1; A(k+1); B(k+2)h0} (10 loads);
// leaves the 2 newest (B(k+2)h0) in flight, drains only loads >=2 phases old.
// P4-end reads of As[c^1]/Bs[c^1] are 2 barriers after the drain (cross-wave
// landing via barrier). Never 0 mid-loop.
//   P1: rdB1(k) | stage A(k+1) h0,h1 | MFMA Q00(A0,B0)
//   P2:          |                    | MFMA Q01(A0,B1); rdA1(k) post
//   P3:          | stage B(k+2) h0    | MFMA Q11(A1,B1); vmcnt(2)
//   P4:          | stage B(k+2) h1    | MFMA Q10(A1,B0); rdA0(k+1)+rdB0(k+1) post
template<int OUT_BF16>
__global__ __launch_bounds__(512, 2) void gemm256(
    const u16* __restrict__ A, const u16* __restrict__ B, void* __restrict__ Cout,
    int M, int N, int K) {
  __shared__ u16 As[2][2][64 * 128];   // [dbuf][half][128 rows x 64 cols]
  __shared__ u16 Bs[2][2][64 * 128];
  const int NKT = K >> 6;              // K-tiles of 64 (requires NKT >= 3)
  int nTN = N >> 8;
  int nwg = gridDim.x;
  int id = ((int)blockIdx.x & 7) * (nwg >> 3) + ((int)blockIdx.x >> 3); // XCD swizzle
  int tm = id / nTN, tn = id % nTN;
  int m0 = tm << 8, n0 = tn << 8;
  int t = threadIdx.x;
  int w = t >> 6, lane = t & 63, lo = lane & 15, hi = lane >> 4;
  int wm = w >> 2, wn = w & 3;
  int rbb = (wn & 1) << 6;

  // staging geometry: thread covers 16B chunk; row = c2*64 + w*8 + lane/8
  int srow = (w << 3) + (lane >> 3);
  int scol = (lane & 7) << 3;          // u16 col base of 8-elem chunk

  auto stageA = [&](int kt, int buf, int h) {
#pragma unroll
    for (int c2 = 0; c2 < 2; ++c2) {
      int row = (c2 << 6) + srow;
      int col = scol ^ ((row & 7) << 3);          // inverse swizzle on source
      async16(A + (size_t)(m0 + (h << 7) + row) * K + (kt << 6) + col,
              (char*)&As[buf][h][0] + (c2 << 13) + (w << 10));
    }
  };
  auto stageB = [&](int kt, int buf, int h) {
#pragma unroll
    for (int c2 = 0; c2 < 2; ++c2) {
      int row = (c2 << 6) + srow;
      int col = scol ^ ((row & 7) << 3);
      async16(B + (size_t)(n0 + (h << 7) + row) * K + (kt << 6) + col,
              (char*)&Bs[buf][h][0] + (c2 << 13) + (w << 10));
    }
  };

  const f32x4 fz = {0.f, 0.f, 0.f, 0.f};
  f32x4 acc[8][4];
#pragma unroll
  for (int i = 0; i < 8; ++i)
#pragma unroll
    for (int j = 0; j < 4; ++j) acc[i][j] = fz;
  bf16x8 af[4][2], bf0[2][2], bf1[2][2];

  auto rdA = [&](int c, int half, bf16x8 (&dst)[4][2]) {   // 8 x ds_read_b128
    const u16* Ab = &As[c][wm][0];
#pragma unroll
    for (int mf = 0; mf < 4; ++mf)
#pragma unroll
      for (int ks = 0; ks < 2; ++ks) {
        int ra = (half << 6) + (mf << 4) + lo;
        dst[mf][ks] = *(const bf16x8*)(Ab + (ra << 6) +
                      (((ks << 5) + (hi << 3)) ^ ((ra & 7) << 3)));
      }
  };
  auto rdB = [&](int c, int bfrag, bf16x8 (&dst)[2][2]) {  // 4 x ds_read_b128
    const u16* Bb = &Bs[c][wn >> 1][0];
#pragma unroll
    for (int nf = 0; nf < 2; ++nf)
#pragma unroll
      for (int ks = 0; ks < 2; ++ks) {
        int rb = rbb + (bfrag << 5) + (nf << 4) + lo;
        dst[nf][ks] = *(const bf16x8*)(Bb + (rb << 6) +
                      (((ks << 5) + (hi << 3)) ^ ((rb & 7) << 3)));
      }
  };
  auto MM = [&](bf16x8 (&a)[4][2], bf16x8 (&b)[2][2], int mo, int no) {
#pragma unroll
    for (int mf = 0; mf < 4; ++mf)
#pragma unroll
      for (int nf = 0; nf < 2; ++nf)
#pragma unroll
        for (int ks = 0; ks < 2; ++ks)
          acc[mo + mf][no + nf] = mfma16(a[mf][ks], b[nf][ks], acc[mo + mf][no + nf]);
  };

  // prologue: tile0 (A+B, 8 loads) + tile1 B (4 loads); drain tile0, keep B(1) flying
  stageA(0, 0, 0); stageA(0, 0, 1);
  stageB(0, 0, 0); stageB(0, 0, 1);
  stageB(1, 1, 0); stageB(1, 1, 1);
  asm volatile("s_waitcnt vmcnt(4)" ::: "memory");
  __builtin_amdgcn_s_barrier();
  rdA(0, 0, af);      // A0(0)
  rdB(0, 0, bf0);     // B0(0)

  for (int kt = 0; kt < NKT; ++kt) {
    int c = kt & 1;
    int kn1 = (kt + 1 == NKT) ? 0 : kt + 1;            // wrap: redundant but uniform
    int kn2 = (kt + 2 >= NKT) ? kt + 2 - NKT : kt + 2;

    // ---- P1: read B1(k) (feeds P2); stage A(k+1) both halves; MFMA Q00
    rdB(c, 1, bf1);
    stageA(kn1, c ^ 1, 0); stageA(kn1, c ^ 1, 1);
    __builtin_amdgcn_s_barrier();
    __builtin_amdgcn_s_setprio(1);
    MM(af, bf0, 0, 0);
    __builtin_amdgcn_s_setprio(0);
    __builtin_amdgcn_s_barrier();

    // ---- P2: MFMA Q01; post-MFMA read A1(k) (feeds P3)
    __builtin_amdgcn_s_setprio(1);
    MM(af, bf1, 0, 2);
    __builtin_amdgcn_s_setprio(0);
    rdA(c, 1, af);
    __builtin_amdgcn_s_barrier();

    // ---- P3: stage B0(k+2); MFMA Q11; counted vmcnt(2) (drains A(k+1),B(k+1);
    //          leaves B(k+2)h0 in flight)
    stageB(kn2, c, 0);
    __builtin_amdgcn_s_barrier();
    __builtin_amdgcn_s_setprio(1);
    MM(af, bf1, 4, 2);
    __builtin_amdgcn_s_setprio(0);
    asm volatile("s_waitcnt vmcnt(2)" ::: "memory");
    __builtin_amdgcn_s_barrier();

    // ---- P4: stage B1(k+2); MFMA Q10; post-MFMA read A0(k+1)+B0(k+1) (feed next P1)
    stageB(kn2, c, 1);
    __builtin_amdgcn_s_barrier();
    __builtin_amdgcn_s_setprio(1);
    MM(af, bf0, 4, 0);
    __builtin_amdgcn_s_setprio(0);
    rdA(c ^ 1, 0, af);
    rdB(c ^ 1, 0, bf0);
    __builtin_amdgcn_s_barrier();
  }

  // epilogue
#pragma unroll
  for (int mf = 0; mf < 8; ++mf)
#pragma unroll
    for (int nf = 0; nf < 4; ++nf)
#pragma unroll
      for (int r = 0; r < 4; ++r) {
        int row = m0 + (wm << 7) + (mf << 4) + (hi << 2) + r;
        int col = n0 + (wn << 6) + (nf << 4) + lo;
        if (OUT_BF16) ((u16*)Cout)[(size_t)row * N + col] = f2bf(acc[mf][nf][r]);
        else          ((float*)Cout)[(size_t)row * N + col] = acc[mf][nf][r];
      }
}

// ---------------- RoPE (in-place on bf16, optional output scale) ----------------
__global__ __launch_bounds__(256) void rope_kernel(u16* __restrict__ X,
                                                   const int* __restrict__ pos,
                                                   int ncols, int pitch, float scale) {
  int idx = blockIdx.x * 256 + threadIdx.x;
  int groups = ncols >> 3;
  int m = idx / groups;
  int gi = idx - m * groups;
  if (m >= MROWS) return;
  int head = gi >> 4;
  int d0 = (gi & 15) << 2;
  float p = (float)pos[m];
  u16* base = X + (size_t)m * pitch + head * 128;
  u16 xa[4], xb[4], oa[4], ob[4];
  *(uint2*)xa = *(const uint2*)(base + d0);
  *(uint2*)xb = *(const uint2*)(base + d0 + 64);
#pragma unroll
  for (int i = 0; i < 4; ++i) {
    float j = (float)(d0 + i);
    float inv = __expf(j * -0.14391156516030342f);  // ln(10000)/64
    float fr = p * inv;
    float s, c;
    sincosf(fr, &s, &c);
    float x1 = bf2f(xa[i]), x2 = bf2f(xb[i]);
    oa[i] = f2bf((x1 * c - x2 * s) * scale);
    ob[i] = f2bf((x2 * c + x1 * s) * scale);
  }
  *(uint2*)(base + d0) = *(uint2*)oa;
  *(uint2*)(base + d0 + 64) = *(uint2*)ob;
}

// ---------------- V transpose: QKV[m][5120 + g*128 + d] -> Vt[(b*8+g)*128 + d][s] ----------------
__global__ __launch_bounds__(256) void transpose_v(const u16* __restrict__ V,
                                                   u16* __restrict__ Vt) {
  int bid = blockIdx.x;
  int s0 = (bid & 31) << 6;
  int bg = bid >> 5;
  int b = bg >> 3, g = bg & 7;
  __shared__ u16 tile[64][128];
  int t = threadIdx.x;
#pragma unroll
  for (int r = 0; r < 4; ++r) {
    int c = (r << 8) + t;
    int row = c >> 4, cc = c & 15;
    *(uint4*)&tile[row][cc * 8] =
        *(const uint4*)(V + (size_t)(b * S_LEN + s0 + row) * QKV_N + g * 128 + cc * 8);
  }
  __syncthreads();
#pragma unroll
  for (int r = 0; r < 4; ++r) {
    int c = (r << 8) + t;
    int d = c >> 3, cs = c & 7;
    u16 tmp[8];
#pragma unroll
    for (int i = 0; i < 8; ++i) tmp[i] = tile[cs * 8 + i][d];
    *(uint4*)(Vt + ((size_t)bg * 128 + d) * S_LEN + s0 + cs * 8) = *(uint4*)tmp;
  }
}

// ---------------- Flash attention (causal, GQA 4:1), swapped-operand layout ----------------
__global__ __launch_bounds__(256) void attn_kernel(
    const u16* __restrict__ Q, const u16* __restrict__ K,
    const u16* __restrict__ Vt, u16* __restrict__ O) {
  int bid = blockIdx.x;
  int qt = 31 - (bid >> 6);          // heavy tiles first
  int bh = bid & 63;
  int b = bh >> 5, h = bh & 31;
  int g = h >> 2;
  __shared__ u16 Kl[64 * 128];
  __shared__ u16 Vl[128 * 64];
  __shared__ u16 Pl[4][16 * 72];     // per-wave P^T / O-bounce, pitch 72
  int t = threadIdx.x, w = t >> 6, lane = t & 63, lo = lane & 15, hi = lane >> 4;

  bf16x8 qf[4];   // B-operand: lane -> Q row (q=lo)
  {
    const u16* qb = Q + (size_t)(b * S_LEN + (qt << 6) + (w << 4) + lo) * QKV_N + h * 128;
#pragma unroll
    for (int kk = 0; kk < 4; ++kk) qf[kk] = *(const bf16x8*)(qb + kk * 32 + hi * 8);
  }
  const f32x4 fz = {0.f, 0.f, 0.f, 0.f};
  f32x4 acc[8];
#pragma unroll
  for (int f = 0; f < 8; ++f) acc[f] = fz;
  float mrun = -1e30f, lrun = 0.f;

  const u16* Kbase = K + (size_t)(b * S_LEN) * QKV_N + g * 128;
  const u16* Vbase = Vt + (size_t)((b << 3) + g) * 128 * S_LEN;

  int ntiles = qt + 1;
  for (int tile = 0; tile < ntiles; ++tile) {
    int s0 = tile << 6;
#pragma unroll
    for (int r = 0; r < 4; ++r) {              // stage K tile [64][128], chunk-swizzled
      int c = (r << 8) + (w << 6) + lane;
      int row = c >> 4, cc = c & 15;
      int src = cc ^ (row & 7);
      async16(Kbase + (size_t)(s0 + row) * QKV_N + src * 8,
              (char*)Kl + (r << 12) + (w << 10));
    }
#pragma unroll
    for (int r = 0; r < 4; ++r) {              // stage V^T tile [128][64], chunk-swizzled
      int c = (r << 8) + (w << 6) + lane;
      int row = c >> 3, cc = c & 7;
      int src = cc ^ (row & 7);
      async16(Vbase + (size_t)row * S_LEN + s0 + src * 8,
              (char*)Vl + (r << 12) + (w << 10));
    }
    __syncthreads();

    f32x4 sf[4];
#pragma unroll
    for (int j = 0; j < 4; ++j) {
      f32x4 sv = fz;
#pragma unroll
      for (int kk = 0; kk < 4; ++kk) {
        int row = (j << 4) + lo;
        int ch = ((kk << 2) + hi) ^ (row & 7);
        bf16x8 kf = *(const bf16x8*)(Kl + row * 128 + ch * 8);
        sv = __builtin_amdgcn_mfma_f32_16x16x32_bf16(kf, qf[kk], sv, 0, 0, 0);
      }
      sf[j] = sv;
    }
    if (tile == qt) {                           // causal mask on diagonal tile
      int q_rel = (w << 4) + lo;
#pragma unroll
      for (int j = 0; j < 4; ++j)
#pragma unroll
        for (int r = 0; r < 4; ++r)
          if (((j << 4) + (hi << 2) + r) > q_rel) sf[j][r] = -1e9f;
    }
    float pmax = sf[0][0];
#pragma unroll
    for (int j = 0; j < 4; ++j)
#pragma unroll
      for (int r = 0; r < 4; ++r) pmax = fmaxf(pmax, sf[j][r]);
    pmax = fmaxf(pmax, __shfl_xor(pmax, 16, 64));
    pmax = fmaxf(pmax, __shfl_xor(pmax, 32, 64));
    if (__any(pmax > mrun + 8.f)) {             // defer-max rescale (THR=8)
      float mn = fmaxf(mrun, pmax);
      float fsc = __expf(mrun - mn);
      mrun = mn;
      lrun *= fsc;
#pragma unroll
      for (int f = 0; f < 8; ++f)
#pragma unroll
        for (int r = 0; r < 4; ++r) acc[f][r] *= fsc;
    }
    float psum = 0.f;
#pragma unroll
    for (int j = 0; j < 4; ++j)
#pragma unroll
      for (int r = 0; r < 4; ++r) {
        float p = __expf(sf[j][r] - mrun);
        sf[j][r] = p;
        psum += p;
      }
    psum += __shfl_xor(psum, 16, 64);
    psum += __shfl_xor(psum, 32, 64);
    lrun += psum;

#pragma unroll
    for (int j = 0; j < 4; ++j) {
      uint2 pk;
      pk.x = cvtpk(sf[j][0], sf[j][1]);
      pk.y = cvtpk(sf[j][2], sf[j][3]);
      *(uint2*)&Pl[w][lo * 72 + (j << 4) + (hi << 2)] = pk;
    }
#pragma unroll
    for (int kk = 0; kk < 2; ++kk) {
      bf16x8 pf = *(const bf16x8*)&Pl[w][lo * 72 + (kk << 5) + (hi << 3)];
#pragma unroll
      for (int f = 0; f < 8; ++f) {
        int vrow = (f << 4) + lo;
        int phys = ((kk << 2) + hi) ^ (vrow & 7);
        bf16x8 vf = *(const bf16x8*)(Vl + vrow * 64 + phys * 8);
        acc[f] = __builtin_amdgcn_mfma_f32_16x16x32_bf16(vf, pf, acc[f], 0, 0, 0);
      }
    }
    __syncthreads();
  }

  float rl = 1.0f / lrun;
#pragma unroll
  for (int half = 0; half < 2; ++half) {
#pragma unroll
    for (int f2 = 0; f2 < 4; ++f2) {
      int f = (half << 2) + f2;
      uint2 pk;
      pk.x = cvtpk(acc[f][0] * rl, acc[f][1] * rl);
      pk.y = cvtpk(acc[f][2] * rl, acc[f][3] * rl);
      *(uint2*)&Pl[w][lo * 72 + (f2 << 4) + (hi << 2)] = pk;
    }
#pragma unroll
    for (int it = 0; it < 2; ++it) {
      int rowq = (lane >> 3) + (it << 3);
      int c8 = lane & 7;
      uint4 val = *(const uint4*)&Pl[w][rowq * 72 + c8 * 8];
      *(uint4*)(O + (size_t)(b * S_LEN + (qt << 6) + (w << 4) + rowq) * 4096 +
                h * 128 + (half << 6) + c8 * 8) = val;
    }
  }
}

// ---------------- launch ----------------
extern "C" void kernel_launch(void* const* d_in, const int* in_sizes, int n_in,
                              void* d_out, int out_size, void* d_ws, size_t ws_size,
                              hipStream_t stream) {
  const float* hidden = (const float*)d_in[0];
  const int* pos = (const int*)d_in[1];
  const float* Wq = (const float*)d_in[2];
  const float* Wk = (const float*)d_in[3];
  const float* Wv = (const float*)d_in[4];
  const float* Wo = (const float*)d_in[5];
  float* out = (float*)d_out;

  u16* hb   = (u16*)d_ws;                 // [4096][4096]
  u16* wqb  = hb   + 16777216;            // [4096][4096]  } contiguous -> fused
  u16* wkb  = wqb  + 16777216;            // [1024][4096]  }   B matrix [6144][4096]
  u16* wvb  = wkb  + 4194304;             // [1024][4096]  }
  u16* wob  = wvb  + 4194304;             // [4096][4096]
  u16* QKVb = wob  + 16777216;            // [4096][6144]
  u16* Vtb  = QKVb + 25165824;            // [16*128][2048]
  u16* Ob   = Vtb  + 4194304;             // [4096][4096]

  cvt_f32_bf16<<<8192, 256, 0, stream>>>(hidden, hb, 16777216);
  cvt_f32_bf16<<<8192, 256, 0, stream>>>(Wq, wqb, 16777216);
  cvt_f32_bf16<<<2048, 256, 0, stream>>>(Wk, wkb, 4194304);
  cvt_f32_bf16<<<2048, 256, 0, stream>>>(Wv, wvb, 4194304);
  cvt_f32_bf16<<<8192, 256, 0, stream>>>(Wo, wob, 16777216);

  gemm256<1><<<384, 512, 0, stream>>>(hb, wqb, QKVb, 4096, QKV_N, 4096);  // fused QKV

  rope_kernel<<<8192, 256, 0, stream>>>(QKVb, pos, 4096, QKV_N, 0.08838834764831845f); // Q (pre-scaled)
  rope_kernel<<<2048, 256, 0, stream>>>(QKVb + 4096, pos, 1024, QKV_N, 1.0f);          // K

  transpose_v<<<512, 256, 0, stream>>>(QKVb + 5120, Vtb);

  attn_kernel<<<2048, 256, 0, stream>>>(QKVb, QKVb + 4096, Vtb, Ob);

  gemm256<0><<<256, 512, 0, stream>>>(Ob, wob, out, 4096, 4096, 4096);
}

// Round 9
// 536.044 us; speedup vs baseline: 1.1661x; 1.0121x over previous
//
#include <hip/hip_runtime.h>

#define S_LEN 2048
#define BATCH 2
#define HID 4096
#define NH 32
#define NKV 8
#define DH 128
#define MROWS (BATCH*S_LEN)   // 4096
#define QKV_N 6144

typedef unsigned short u16;
typedef unsigned int u32;
typedef __bf16 bf16x8 __attribute__((ext_vector_type(8)));
typedef float f32x4 __attribute__((ext_vector_type(4)));
typedef u16 u16x8 __attribute__((ext_vector_type(8)));

__device__ __forceinline__ u16 f2bf(float f) {           // round-half-up (2 insts)
  union { float f; u32 u; } v; v.f = f;
  return (u16)((v.u + 0x8000u) >> 16);
}
__device__ __forceinline__ float bf2f(u16 h) {
  union { u32 u; float f; } v; v.u = ((u32)h) << 16;
  return v.f;
}
__device__ __forceinline__ u32 cvtpk(float a, float b) { // packs bf16(a)|bf16(b)<<16
  u32 r;
  asm("v_cvt_pk_bf16_f32 %0, %1, %2" : "=v"(r) : "v"(a), "v"(b));
  return r;
}
__device__ __forceinline__ void async16(const void* g, void* l) {
  __builtin_amdgcn_global_load_lds(
      (const __attribute__((address_space(1))) u32*)g,
      (__attribute__((address_space(3))) u32*)l, 16, 0, 0);
}
__device__ __forceinline__ f32x4 mfma16(bf16x8 a, bf16x8 b, f32x4 c) {
  return __builtin_amdgcn_mfma_f32_16x16x32_bf16(a, b, c, 0, 0, 0);
}

// ---------------- fp32 -> bf16 conversion ----------------
__global__ __launch_bounds__(256) void cvt_f32_bf16(const float* __restrict__ in,
                                                    u16* __restrict__ out, int n) {
  int i0 = (blockIdx.x * 256 + threadIdx.x) * 8;
  if (i0 >= n) return;
  float4 a = *(const float4*)(in + i0);
  float4 b = *(const float4*)(in + i0 + 4);
  u16x8 r;
  r[0]=f2bf(a.x); r[1]=f2bf(a.y); r[2]=f2bf(a.z); r[3]=f2bf(a.w);
  r[4]=f2bf(b.x); r[5]=f2bf(b.y); r[6]=f2bf(b.z); r[7]=f2bf(b.w);
  *(u16x8*)(out + i0) = r;
}

// ---------------- 256x256 NT bf16 GEMM, r8: 2-D XCD sub-grid locality ------
// 512 thr = 8 waves (2M x 4N); BK=64; per-wave C = 128x64 (8x4 frags 16x16).
// LDS 128KB [dbuf2][half2][128x64] per matrix; 3-bit chunk swizzle (0 conflicts, r5).
// Schedule identical to r7 (read-ahead + counted vmcnt(2)).
// r8 theory: both GEMMs are FETCH-bound (~362MB @ ~1.6TB/s regardless of FLOPs;
// QKV and O-proj identical bytes+time). Old 1-D XCD swizzle gave each XCD a
// row-STRIP (r+c panels = 2+16 per XCD for O-proj). New 2-D map gives each XCD
// a ~square SR x SC sub-grid: fetch/XCD = (SR+SC) panels, minimized.
//   xcd = bid&7 (HW round-robin), l = bid>>3 (row-major within sub-grid)
//   tm = (xcd/XC)*SR + l/SC ; tn = (xcd%XC)*SC + l%SC
// QKV (16x24): XCD-grid 2x4, sub 8x6 -> 14 panels/XCD (was 26).
// Oproj(16x16): XCD-grid 4x2, sub 4x8 -> 12 panels/XCD (was 18).
template<int OUT_BF16>
__global__ __launch_bounds__(512, 2) void gemm256(
    const u16* __restrict__ A, const u16* __restrict__ B, void* __restrict__ Cout,
    int M, int N, int K, int XC, int SR, int SC) {
  __shared__ u16 As[2][2][64 * 128];   // [dbuf][half][128 rows x 64 cols]
  __shared__ u16 Bs[2][2][64 * 128];
  const int NKT = K >> 6;              // K-tiles of 64 (requires NKT >= 3)
  int bid = (int)blockIdx.x;
  int xcd = bid & 7, l = bid >> 3;
  int tm = (xcd / XC) * SR + l / SC;
  int tn = (xcd % XC) * SC + l % SC;
  int m0 = tm << 8, n0 = tn << 8;
  int t = threadIdx.x;
  int w = t >> 6, lane = t & 63, lo = lane & 15, hi = lane >> 4;
  int wm = w >> 2, wn = w & 3;
  int rbb = (wn & 1) << 6;

  // staging geometry: thread covers 16B chunk; row = c2*64 + w*8 + lane/8
  int srow = (w << 3) + (lane >> 3);
  int scol = (lane & 7) << 3;          // u16 col base of 8-elem chunk

  auto stageA = [&](int kt, int buf, int h) {
#pragma unroll
    for (int c2 = 0; c2 < 2; ++c2) {
      int row = (c2 << 6) + srow;
      int col = scol ^ ((row & 7) << 3);          // inverse swizzle on source
      async16(A + (size_t)(m0 + (h << 7) + row) * K + (kt << 6) + col,
              (char*)&As[buf][h][0] + (c2 << 13) + (w << 10));
    }
  };
  auto stageB = [&](int kt, int buf, int h) {
#pragma unroll
    for (int c2 = 0; c2 < 2; ++c2) {
      int row = (c2 << 6) + srow;
      int col = scol ^ ((row & 7) << 3);
      async16(B + (size_t)(n0 + (h << 7) + row) * K + (kt << 6) + col,
              (char*)&Bs[buf][h][0] + (c2 << 13) + (w << 10));
    }
  };

  const f32x4 fz = {0.f, 0.f, 0.f, 0.f};
  f32x4 acc[8][4];
#pragma unroll
  for (int i = 0; i < 8; ++i)
#pragma unroll
    for (int j = 0; j < 4; ++j) acc[i][j] = fz;
  bf16x8 af[4][2], bf0[2][2], bf1[2][2];

  auto rdA = [&](int c, int half, bf16x8 (&dst)[4][2]) {   // 8 x ds_read_b128
    const u16* Ab = &As[c][wm][0];
#pragma unroll
    for (int mf = 0; mf < 4; ++mf)
#pragma unroll
      for (int ks = 0; ks < 2; ++ks) {
        int ra = (half << 6) + (mf << 4) + lo;
        dst[mf][ks] = *(const bf16x8*)(Ab + (ra << 6) +
                      (((ks << 5) + (hi << 3)) ^ ((ra & 7) << 3)));
      }
  };
  auto rdB = [&](int c, int bfrag, bf16x8 (&dst)[2][2]) {  // 4 x ds_read_b128
    const u16* Bb = &Bs[c][wn >> 1][0];
#pragma unroll
    for (int nf = 0; nf < 2; ++nf)
#pragma unroll
      for (int ks = 0; ks < 2; ++ks) {
        int rb = rbb + (bfrag << 5) + (nf << 4) + lo;
        dst[nf][ks] = *(const bf16x8*)(Bb + (rb << 6) +
                      (((ks << 5) + (hi << 3)) ^ ((rb & 7) << 3)));
      }
  };
  auto MM = [&](bf16x8 (&a)[4][2], bf16x8 (&b)[2][2], int mo, int no) {
#pragma unroll
    for (int mf = 0; mf < 4; ++mf)
#pragma unroll
      for (int nf = 0; nf < 2; ++nf)
#pragma unroll
        for (int ks = 0; ks < 2; ++ks)
          acc[mo + mf][no + nf] = mfma16(a[mf][ks], b[nf][ks], acc[mo + mf][no + nf]);
  };

  // prologue: tile0 (A+B, 8 loads) + tile1 B (4 loads); drain tile0, keep B(1) flying
  stageA(0, 0, 0); stageA(0, 0, 1);
  stageB(0, 0, 0); stageB(0, 0, 1);
  stageB(1, 1, 0); stageB(1, 1, 1);
  asm volatile("s_waitcnt vmcnt(4)" ::: "memory");
  __builtin_amdgcn_s_barrier();
  rdA(0, 0, af);      // A0(0)
  rdB(0, 0, bf0);     // B0(0)

  for (int kt = 0; kt < NKT; ++kt) {
    int c = kt & 1;
    int kn1 = (kt + 1 == NKT) ? 0 : kt + 1;            // wrap: redundant but uniform
    int kn2 = (kt + 2 >= NKT) ? kt + 2 - NKT : kt + 2;

    // ---- P1: read B1(k) (feeds P2); stage A(k+1) both halves; MFMA Q00
    rdB(c, 1, bf1);
    stageA(kn1, c ^ 1, 0); stageA(kn1, c ^ 1, 1);
    __builtin_amdgcn_s_barrier();
    __builtin_amdgcn_s_setprio(1);
    MM(af, bf0, 0, 0);
    __builtin_amdgcn_s_setprio(0);
    __builtin_amdgcn_s_barrier();

    // ---- P2: MFMA Q01; post-MFMA read A1(k) (feeds P3)
    __builtin_amdgcn_s_setprio(1);
    MM(af, bf1, 0, 2);
    __builtin_amdgcn_s_setprio(0);
    rdA(c, 1, af);
    __builtin_amdgcn_s_barrier();

    // ---- P3: stage B0(k+2); MFMA Q11; counted vmcnt(2) (drains A(k+1),B(k+1);
    //          leaves B(k+2)h0 in flight)
    stageB(kn2, c, 0);
    __builtin_amdgcn_s_barrier();
    __builtin_amdgcn_s_setprio(1);
    MM(af, bf1, 4, 2);
    __builtin_amdgcn_s_setprio(0);
    asm volatile("s_waitcnt vmcnt(2)" ::: "memory");
    __builtin_amdgcn_s_barrier();

    // ---- P4: stage B1(k+2); MFMA Q10; post-MFMA read A0(k+1)+B0(k+1) (feed next P1)
    stageB(kn2, c, 1);
    __builtin_amdgcn_s_barrier();
    __builtin_amdgcn_s_setprio(1);
    MM(af, bf0, 4, 0);
    __builtin_amdgcn_s_setprio(0);
    rdA(c ^ 1, 0, af);
    rdB(c ^ 1, 0, bf0);
    __builtin_amdgcn_s_barrier();
  }

  // epilogue
#pragma unroll
  for (int mf = 0; mf < 8; ++mf)
#pragma unroll
    for (int nf = 0; nf < 4; ++nf)
#pragma unroll
      for (int r = 0; r < 4; ++r) {
        int row = m0 + (wm << 7) + (mf << 4) + (hi << 2) + r;
        int col = n0 + (wn << 6) + (nf << 4) + lo;
        if (OUT_BF16) ((u16*)Cout)[(size_t)row * N + col] = f2bf(acc[mf][nf][r]);
        else          ((float*)Cout)[(size_t)row * N + col] = acc[mf][nf][r];
      }
}

// ---------------- RoPE (in-place on bf16, optional output scale) ----------------
__global__ __launch_bounds__(256) void rope_kernel(u16* __restrict__ X,
                                                   const int* __restrict__ pos,
                                                   int ncols, int pitch, float scale) {
  int idx = blockIdx.x * 256 + threadIdx.x;
  int groups = ncols >> 3;
  int m = idx / groups;
  int gi = idx - m * groups;
  if (m >= MROWS) return;
  int head = gi >> 4;
  int d0 = (gi & 15) << 2;
  float p = (float)pos[m];
  u16* base = X + (size_t)m * pitch + head * 128;
  u16 xa[4], xb[4], oa[4], ob[4];
  *(uint2*)xa = *(const uint2*)(base + d0);
  *(uint2*)xb = *(const uint2*)(base + d0 + 64);
#pragma unroll
  for (int i = 0; i < 4; ++i) {
    float j = (float)(d0 + i);
    float inv = __expf(j * -0.14391156516030342f);  // ln(10000)/64
    float fr = p * inv;
    float s, c;
    sincosf(fr, &s, &c);
    float x1 = bf2f(xa[i]), x2 = bf2f(xb[i]);
    oa[i] = f2bf((x1 * c - x2 * s) * scale);
    ob[i] = f2bf((x2 * c + x1 * s) * scale);
  }
  *(uint2*)(base + d0) = *(uint2*)oa;
  *(uint2*)(base + d0 + 64) = *(uint2*)ob;
}

// ---------------- V transpose: QKV[m][5120 + g*128 + d] -> Vt[(b*8+g)*128 + d][s] ----------------
__global__ __launch_bounds__(256) void transpose_v(const u16* __restrict__ V,
                                                   u16* __restrict__ Vt) {
  int bid = blockIdx.x;
  int s0 = (bid & 31) << 6;
  int bg = bid >> 5;
  int b = bg >> 3, g = bg & 7;
  __shared__ u16 tile[64][128];
  int t = threadIdx.x;
#pragma unroll
  for (int r = 0; r < 4; ++r) {
    int c = (r << 8) + t;
    int row = c >> 4, cc = c & 15;
    *(uint4*)&tile[row][cc * 8] =
        *(const uint4*)(V + (size_t)(b * S_LEN + s0 + row) * QKV_N + g * 128 + cc * 8);
  }
  __syncthreads();
#pragma unroll
  for (int r = 0; r < 4; ++r) {
    int c = (r << 8) + t;
    int d = c >> 3, cs = c & 7;
    u16 tmp[8];
#pragma unroll
    for (int i = 0; i < 8; ++i) tmp[i] = tile[cs * 8 + i][d];
    *(uint4*)(Vt + ((size_t)bg * 128 + d) * S_LEN + s0 + cs * 8) = *(uint4*)tmp;
  }
}

// ---------------- Flash attention (causal, GQA 4:1), swapped-operand layout ----------------
__global__ __launch_bounds__(256) void attn_kernel(
    const u16* __restrict__ Q, const u16* __restrict__ K,
    const u16* __restrict__ Vt, u16* __restrict__ O) {
  int bid = blockIdx.x;
  int qt = 31 - (bid >> 6);          // heavy tiles first
  int bh = bid & 63;
  int b = bh >> 5, h = bh & 31;
  int g = h >> 2;
  __shared__ u16 Kl[64 * 128];
  __shared__ u16 Vl[128 * 64];
  __shared__ u16 Pl[4][16 * 72];     // per-wave P^T / O-bounce, pitch 72
  int t = threadIdx.x, w = t >> 6, lane = t & 63, lo = lane & 15, hi = lane >> 4;

  bf16x8 qf[4];   // B-operand: lane -> Q row (q=lo)
  {
    const u16* qb = Q + (size_t)(b * S_LEN + (qt << 6) + (w << 4) + lo) * QKV_N + h * 128;
#pragma unroll
    for (int kk = 0; kk < 4; ++kk) qf[kk] = *(const bf16x8*)(qb + kk * 32 + hi * 8);
  }
  const f32x4 fz = {0.f, 0.f, 0.f, 0.f};
  f32x4 acc[8];
#pragma unroll
  for (int f = 0; f < 8; ++f) acc[f] = fz;
  float mrun = -1e30f, lrun = 0.f;

  const u16* Kbase = K + (size_t)(b * S_LEN) * QKV_N + g * 128;
  const u16* Vbase = Vt + (size_t)((b << 3) + g) * 128 * S_LEN;

  int ntiles = qt + 1;
  for (int tile = 0; tile < ntiles; ++tile) {
    int s0 = tile << 6;
#pragma unroll
    for (int r = 0; r < 4; ++r) {              // stage K tile [64][128], chunk-swizzled
      int c = (r << 8) + (w << 6) + lane;
      int row = c >> 4, cc = c & 15;
      int src = cc ^ (row & 7);
      async16(Kbase + (size_t)(s0 + row) * QKV_N + src * 8,
              (char*)Kl + (r << 12) + (w << 10));
    }
#pragma unroll
    for (int r = 0; r < 4; ++r) {              // stage V^T tile [128][64], chunk-swizzled
      int c = (r << 8) + (w << 6) + lane;
      int row = c >> 3, cc = c & 7;
      int src = cc ^ (row & 7);
      async16(Vbase + (size_t)row * S_LEN + s0 + src * 8,
              (char*)Vl + (r << 12) + (w << 10));
    }
    __syncthreads();

    f32x4 sf[4];
#pragma unroll
    for (int j = 0; j < 4; ++j) {
      f32x4 sv = fz;
#pragma unroll
      for (int kk = 0; kk < 4; ++kk) {
        int row = (j << 4) + lo;
        int ch = ((kk << 2) + hi) ^ (row & 7);
        bf16x8 kf = *(const bf16x8*)(Kl + row * 128 + ch * 8);
        sv = __builtin_amdgcn_mfma_f32_16x16x32_bf16(kf, qf[kk], sv, 0, 0, 0);
      }
      sf[j] = sv;
    }
    if (tile == qt) {                           // causal mask on diagonal tile
      int q_rel = (w << 4) + lo;
#pragma unroll
      for (int j = 0; j < 4; ++j)
#pragma unroll
        for (int r = 0; r < 4; ++r)
          if (((j << 4) + (hi << 2) + r) > q_rel) sf[j][r] = -1e9f;
    }
    float pmax = sf[0][0];
#pragma unroll
    for (int j = 0; j < 4; ++j)
#pragma unroll
      for (int r = 0; r < 4; ++r) pmax = fmaxf(pmax, sf[j][r]);
    pmax = fmaxf(pmax, __shfl_xor(pmax, 16, 64));
    pmax = fmaxf(pmax, __shfl_xor(pmax, 32, 64));
    if (__any(pmax > mrun + 8.f)) {             // defer-max rescale (THR=8)
      float mn = fmaxf(mrun, pmax);
      float fsc = __expf(mrun - mn);
      mrun = mn;
      lrun *= fsc;
#pragma unroll
      for (int f = 0; f < 8; ++f)
#pragma unroll
        for (int r = 0; r < 4; ++r) acc[f][r] *= fsc;
    }
    float psum = 0.f;
#pragma unroll
    for (int j = 0; j < 4; ++j)
#pragma unroll
      for (int r = 0; r < 4; ++r) {
        float p = __expf(sf[j][r] - mrun);
        sf[j][r] = p;
        psum += p;
      }
    psum += __shfl_xor(psum, 16, 64);
    psum += __shfl_xor(psum, 32, 64);
    lrun += psum;

#pragma unroll
    for (int j = 0; j < 4; ++j) {
      uint2 pk;
      pk.x = cvtpk(sf[j][0], sf[j][1]);
      pk.y = cvtpk(sf[j][2], sf[j][3]);
      *(uint2*)&Pl[w][lo * 72 + (j << 4) + (hi << 2)] = pk;
    }
#pragma unroll
    for (int kk = 0; kk < 2; ++kk) {
      bf16x8 pf = *(const bf16x8*)&Pl[w][lo * 72 + (kk << 5) + (hi << 3)];
#pragma unroll
      for (int f = 0; f < 8; ++f) {
        int vrow = (f << 4) + lo;
        int phys = ((kk << 2) + hi) ^ (vrow & 7);
        bf16x8 vf = *(const bf16x8*)(Vl + vrow * 64 + phys * 8);
        acc[f] = __builtin_amdgcn_mfma_f32_16x16x32_bf16(vf, pf, acc[f], 0, 0, 0);
      }
    }
    __syncthreads();
  }

  float rl = 1.0f / lrun;
#pragma unroll
  for (int half = 0; half < 2; ++half) {
#pragma unroll
    for (int f2 = 0; f2 < 4; ++f2) {
      int f = (half << 2) + f2;
      uint2 pk;
      pk.x = cvtpk(acc[f][0] * rl, acc[f][1] * rl);
      pk.y = cvtpk(acc[f][2] * rl, acc[f][3] * rl);
      *(uint2*)&Pl[w][lo * 72 + (f2 << 4) + (hi << 2)] = pk;
    }
#pragma unroll
    for (int it = 0; it < 2; ++it) {
      int rowq = (lane >> 3) + (it << 3);
      int c8 = lane & 7;
      uint4 val = *(const uint4*)&Pl[w][rowq * 72 + c8 * 8];
      *(uint4*)(O + (size_t)(b * S_LEN + (qt << 6) + (w << 4) + rowq) * 4096 +
                h * 128 + (half << 6) + c8 * 8) = val;
    }
  }
}

// ---------------- launch ----------------
extern "C" void kernel_launch(void* const* d_in, const int* in_sizes, int n_in,
                              void* d_out, int out_size, void* d_ws, size_t ws_size,
                              hipStream_t stream) {
  const float* hidden = (const float*)d_in[0];
  const int* pos = (const int*)d_in[1];
  const float* Wq = (const float*)d_in[2];
  const float* Wk = (const float*)d_in[3];
  const float* Wv = (const float*)d_in[4];
  const float* Wo = (const float*)d_in[5];
  float* out = (float*)d_out;

  u16* hb   = (u16*)d_ws;                 // [4096][4096]
  u16* wqb  = hb   + 16777216;            // [4096][4096]  } contiguous -> fused
  u16* wkb  = wqb  + 16777216;            // [1024][4096]  }   B matrix [6144][4096]
  u16* wvb  = wkb  + 4194304;             // [1024][4096]  }
  u16* wob  = wvb  + 4194304;             // [4096][4096]
  u16* QKVb = wob  + 16777216;            // [4096][6144]
  u16* Vtb  = QKVb + 25165824;            // [16*128][2048]
  u16* Ob   = Vtb  + 4194304;             // [4096][4096]

  cvt_f32_bf16<<<8192, 256, 0, stream>>>(hidden, hb, 16777216);
  cvt_f32_bf16<<<8192, 256, 0, stream>>>(Wq, wqb, 16777216);
  cvt_f32_bf16<<<2048, 256, 0, stream>>>(Wk, wkb, 4194304);
  cvt_f32_bf16<<<2048, 256, 0, stream>>>(Wv, wvb, 4194304);
  cvt_f32_bf16<<<8192, 256, 0, stream>>>(Wo, wob, 16777216);

  // QKV: grid 16x24 tiles; XCD-grid 2x4, sub-grid 8x6 (XC=4, SR=8, SC=6)
  gemm256<1><<<384, 512, 0, stream>>>(hb, wqb, QKVb, 4096, QKV_N, 4096, 4, 8, 6);

  rope_kernel<<<8192, 256, 0, stream>>>(QKVb, pos, 4096, QKV_N, 0.08838834764831845f); // Q (pre-scaled)
  rope_kernel<<<2048, 256, 0, stream>>>(QKVb + 4096, pos, 1024, QKV_N, 1.0f);          // K

  transpose_v<<<512, 256, 0, stream>>>(QKVb + 5120, Vtb);

  attn_kernel<<<2048, 256, 0, stream>>>(QKVb, QKVb + 4096, Vtb, Ob);

  // O-proj: grid 16x16 tiles; XCD-grid 4x2, sub-grid 4x8 (XC=2, SR=4, SC=8)
  gemm256<0><<<256, 512, 0, stream>>>(Ob, wob, out, 4096, 4096, 4096, 2, 4, 8);
}